// Round 11
// baseline (1671.672 us; speedup 1.0000x reference)
//
#include <hip/hip_runtime.h>
#include <math.h>

// MoIE transformer block on MFMA via f16-split f32 emulation.
// R11: fused kernels stage 5 planes in LDS (50KB -> 3 blocks/CU, was 60KB/2);
//      W1 becomes a per-lane register-fragment pipeline (R6 mechanics).
//      Products unchanged from R10 (7 fused / 3 scores / 3 pv / 4 prc).
// B=4, S=2048, D=1024.
#define Dd 1024
#define Ss 2048
#define NBATCH 4

static constexpr size_t SDsz = (size_t)Ss * Dd;   // 2M elems
static constexpr size_t MIsz = (size_t)Dd * Dd;   // 1M elems
static constexpr size_t SSsz = (size_t)Ss * Ss;   // 4M elems
static constexpr float LN_EPS_ = 1e-5f;
static constexpr float GATE_EPS_ = 1e-9f;
static constexpr float SCALE_ = 1.0f / 32.0f;     // 1/sqrt(1024), exact

typedef _Float16 f16;
typedef _Float16 f16x8 __attribute__((ext_vector_type(8)));
typedef _Float16 f16x4 __attribute__((ext_vector_type(4)));
typedef float f32x4 __attribute__((ext_vector_type(4)));

__device__ __forceinline__ float silu_f(float v) { return v / (1.0f + __expf(-v)); }

__device__ __forceinline__ void split2(float x, f16& a, f16& b) {
  a = (f16)x; b = (f16)(x - (float)a);
}

// ---------------- block reductions (256 threads = 4 waves) ----------------
__device__ __forceinline__ float2 block_sum2(float2 v) {
#pragma unroll
  for (int o = 32; o > 0; o >>= 1) { v.x += __shfl_down(v.x, o); v.y += __shfl_down(v.y, o); }
  __shared__ float2 sm2[4];
  if ((threadIdx.x & 63) == 0) sm2[threadIdx.x >> 6] = v;
  __syncthreads();
  float2 r; r.x = sm2[0].x + sm2[1].x + sm2[2].x + sm2[3].x;
  r.y = sm2[0].y + sm2[1].y + sm2[2].y + sm2[3].y;
  __syncthreads();
  return r;
}
__device__ __forceinline__ float block_sum1(float v) {
#pragma unroll
  for (int o = 32; o > 0; o >>= 1) v += __shfl_down(v, o);
  __shared__ float sm1[4];
  if ((threadIdx.x & 63) == 0) sm1[threadIdx.x >> 6] = v;
  __syncthreads();
  float r = sm1[0] + sm1[1] + sm1[2] + sm1[3];
  __syncthreads();
  return r;
}
__device__ __forceinline__ float block_max1(float v) {
#pragma unroll
  for (int o = 32; o > 0; o >>= 1) v = fmaxf(v, __shfl_down(v, o));
  __shared__ float smm[4];
  if ((threadIdx.x & 63) == 0) smm[threadIdx.x >> 6] = v;
  __syncthreads();
  float r = fmaxf(fmaxf(smm[0], smm[1]), fmaxf(smm[2], smm[3]));
  __syncthreads();
  return r;
}

// ---------------- multi-plane MFMA GEMM core (16x16x32, reg-staged) ----------------
// acc += sum_{i+j<=MAXSUM} A_i * B_j^T over K; tile 128x128, 4 waves each 64x64.
// LDS rows padded to 40 f16 (80B).
template<int PLANES, int MAXSUM>
__device__ __forceinline__ void mp_core(
    f16* __restrict__ smem,
    const f16* __restrict__ Ap0, const f16* __restrict__ Ap1,
    const f16* __restrict__ Bp0, const f16* __restrict__ Bp1,
    int lda, int ldb, int m0, int n0, int kt_end, f32x4 acc[4][4]) {
  const f16* Ap[2] = {Ap0, Ap1};
  const f16* Bp[2] = {Bp0, Bp1};
  const int tid = threadIdx.x;
  const int l = tid & 63;
  const int wv = tid >> 6;
  const int wr = (wv >> 1) * 64, wc = (wv & 1) * 64;
  const int fl = l & 15, fq = l >> 4;
  const int r0 = tid >> 2, kc = (tid & 3) * 8;

  f16x8 ra[PLANES][2], rb[PLANES][2];
#pragma unroll
  for (int p = 0; p < PLANES; ++p) {
    ra[p][0] = *(const f16x8*)(Ap[p] + (size_t)(m0 + r0) * lda + kc);
    ra[p][1] = *(const f16x8*)(Ap[p] + (size_t)(m0 + 64 + r0) * lda + kc);
    rb[p][0] = *(const f16x8*)(Bp[p] + (size_t)(n0 + r0) * ldb + kc);
    rb[p][1] = *(const f16x8*)(Bp[p] + (size_t)(n0 + 64 + r0) * ldb + kc);
  }
  for (int kt = 0; kt < kt_end; ++kt) {
    __syncthreads();
#pragma unroll
    for (int p = 0; p < PLANES; ++p) {
      *(f16x8*)(smem + p * 5120 + r0 * 40 + kc) = ra[p][0];
      *(f16x8*)(smem + p * 5120 + (64 + r0) * 40 + kc) = ra[p][1];
      *(f16x8*)(smem + (PLANES + p) * 5120 + r0 * 40 + kc) = rb[p][0];
      *(f16x8*)(smem + (PLANES + p) * 5120 + (64 + r0) * 40 + kc) = rb[p][1];
    }
    __syncthreads();
    if (kt + 1 < kt_end) {
      const int ko = (kt + 1) * 32 + kc;
#pragma unroll
      for (int p = 0; p < PLANES; ++p) {
        ra[p][0] = *(const f16x8*)(Ap[p] + (size_t)(m0 + r0) * lda + ko);
        ra[p][1] = *(const f16x8*)(Ap[p] + (size_t)(m0 + 64 + r0) * lda + ko);
        rb[p][0] = *(const f16x8*)(Bp[p] + (size_t)(n0 + r0) * ldb + ko);
        rb[p][1] = *(const f16x8*)(Bp[p] + (size_t)(n0 + 64 + r0) * ldb + ko);
      }
    }
    f16x8 af[PLANES][4];
#pragma unroll
    for (int p = 0; p < PLANES; ++p)
#pragma unroll
      for (int fr = 0; fr < 4; ++fr)
        af[p][fr] = *(const f16x8*)(smem + p * 5120 + (wr + fr * 16 + fl) * 40 + fq * 8);
#pragma unroll
    for (int fc = 0; fc < 4; ++fc) {
      f16x8 bf[PLANES];
#pragma unroll
      for (int p = 0; p < PLANES; ++p)
        bf[p] = *(const f16x8*)(smem + (PLANES + p) * 5120 + (wc + fc * 16 + fl) * 40 + fq * 8);
#pragma unroll
      for (int i = 0; i < PLANES; ++i)
#pragma unroll
        for (int j = 0; j < PLANES; ++j)
          if (i + j <= MAXSUM) {
#pragma unroll
            for (int fr = 0; fr < 4; ++fr)
              acc[fr][fc] = __builtin_amdgcn_mfma_f32_16x16x32_f16(af[i][fr], bf[j], acc[fr][fc], 0, 0, 0);
          }
    }
  }
}

// ---------------- fused dual-acc core (5 LDS planes + W1 reg pipeline) ----------------
// LDS planes: A0,A1 (h lo/hi), W0, P0, P1.  Reg-pipelined: W1 B-fragments.
// acc1 += h@W^T   products (0,0),(0,1 via reg),(1,0)
// acc2 += h@P^T   products (0,0),(0,1),(1,0),(1,1)
__device__ __forceinline__ void fused_core(
    f16* __restrict__ smem,
    const f16* __restrict__ A0p, const f16* __restrict__ A1p,
    const f16* __restrict__ W0p, const f16* __restrict__ W1p,
    const f16* __restrict__ P0p, const f16* __restrict__ P1p,
    int lda, int ldb, int m0, int n0, int kt_end,
    f32x4 acc1[4][4], f32x4 acc2[4][4]) {
  const f16* As[2] = {A0p, A1p};
  const f16* Bs[3] = {W0p, P0p, P1p};
  const int tid = threadIdx.x;
  const int l = tid & 63;
  const int wv = tid >> 6;
  const int wr = (wv >> 1) * 64, wc = (wv & 1) * 64;
  const int fl = l & 15, fq = l >> 4;
  const int r0 = tid >> 2, kc = (tid & 3) * 8;

  f16x8 ra[2][2], rb[3][2];
#pragma unroll
  for (int p = 0; p < 2; ++p) {
    ra[p][0] = *(const f16x8*)(As[p] + (size_t)(m0 + r0) * lda + kc);
    ra[p][1] = *(const f16x8*)(As[p] + (size_t)(m0 + 64 + r0) * lda + kc);
  }
#pragma unroll
  for (int p = 0; p < 3; ++p) {
    rb[p][0] = *(const f16x8*)(Bs[p] + (size_t)(n0 + r0) * ldb + kc);
    rb[p][1] = *(const f16x8*)(Bs[p] + (size_t)(n0 + 64 + r0) * ldb + kc);
  }
  // W1 per-lane B-fragment pipeline (kt=0 prologue)
  f16x8 pw1[4];
#pragma unroll
  for (int f = 0; f < 4; ++f)
    pw1[f] = *(const f16x8*)(W1p + (size_t)(n0 + wc + f * 16 + fl) * ldb + fq * 8);

  for (int kt = 0; kt < kt_end; ++kt) {
    __syncthreads();
#pragma unroll
    for (int p = 0; p < 2; ++p) {
      *(f16x8*)(smem + p * 5120 + r0 * 40 + kc) = ra[p][0];
      *(f16x8*)(smem + p * 5120 + (64 + r0) * 40 + kc) = ra[p][1];
    }
#pragma unroll
    for (int p = 0; p < 3; ++p) {
      *(f16x8*)(smem + (2 + p) * 5120 + r0 * 40 + kc) = rb[p][0];
      *(f16x8*)(smem + (2 + p) * 5120 + (64 + r0) * 40 + kc) = rb[p][1];
    }
    __syncthreads();
    f16x8 nw1[4];
    if (kt + 1 < kt_end) {
      const int ko = (kt + 1) * 32 + kc;
#pragma unroll
      for (int p = 0; p < 2; ++p) {
        ra[p][0] = *(const f16x8*)(As[p] + (size_t)(m0 + r0) * lda + ko);
        ra[p][1] = *(const f16x8*)(As[p] + (size_t)(m0 + 64 + r0) * lda + ko);
      }
#pragma unroll
      for (int p = 0; p < 3; ++p) {
        rb[p][0] = *(const f16x8*)(Bs[p] + (size_t)(n0 + r0) * ldb + ko);
        rb[p][1] = *(const f16x8*)(Bs[p] + (size_t)(n0 + 64 + r0) * ldb + ko);
      }
      const int kf = (kt + 1) * 32 + fq * 8;
#pragma unroll
      for (int f = 0; f < 4; ++f)
        nw1[f] = *(const f16x8*)(W1p + (size_t)(n0 + wc + f * 16 + fl) * ldb + kf);
    }
    f16x8 af0[4], af1[4];
#pragma unroll
    for (int fr = 0; fr < 4; ++fr) {
      af0[fr] = *(const f16x8*)(smem + 0 * 5120 + (wr + fr * 16 + fl) * 40 + fq * 8);
      af1[fr] = *(const f16x8*)(smem + 1 * 5120 + (wr + fr * 16 + fl) * 40 + fq * 8);
    }
#pragma unroll
    for (int fc = 0; fc < 4; ++fc) {
      f16x8 bw0 = *(const f16x8*)(smem + 2 * 5120 + (wc + fc * 16 + fl) * 40 + fq * 8);
      f16x8 bp0 = *(const f16x8*)(smem + 3 * 5120 + (wc + fc * 16 + fl) * 40 + fq * 8);
      f16x8 bp1 = *(const f16x8*)(smem + 4 * 5120 + (wc + fc * 16 + fl) * 40 + fq * 8);
      f16x8 bw1 = pw1[fc];
#pragma unroll
      for (int fr = 0; fr < 4; ++fr) {
        acc1[fr][fc] = __builtin_amdgcn_mfma_f32_16x16x32_f16(af0[fr], bw0, acc1[fr][fc], 0, 0, 0);
        acc2[fr][fc] = __builtin_amdgcn_mfma_f32_16x16x32_f16(af0[fr], bp0, acc2[fr][fc], 0, 0, 0);
        acc1[fr][fc] = __builtin_amdgcn_mfma_f32_16x16x32_f16(af0[fr], bw1, acc1[fr][fc], 0, 0, 0);
        acc2[fr][fc] = __builtin_amdgcn_mfma_f32_16x16x32_f16(af0[fr], bp1, acc2[fr][fc], 0, 0, 0);
        acc1[fr][fc] = __builtin_amdgcn_mfma_f32_16x16x32_f16(af1[fr], bw0, acc1[fr][fc], 0, 0, 0);
        acc2[fr][fc] = __builtin_amdgcn_mfma_f32_16x16x32_f16(af1[fr], bp0, acc2[fr][fc], 0, 0, 0);
        acc2[fr][fc] = __builtin_amdgcn_mfma_f32_16x16x32_f16(af1[fr], bp1, acc2[fr][fc], 0, 0, 0);
      }
    }
    if (kt + 1 < kt_end) {
#pragma unroll
      for (int f = 0; f < 4; ++f) pw1[f] = nw1[f];
    }
  }
}

// epilogue iterators
template<class F>
__device__ __forceinline__ void epilogue(const f32x4 acc[4][4], int m0, int n0, F&& f) {
  const int tid = threadIdx.x;
  const int l = tid & 63;
  const int wv = tid >> 6;
  const int wr = (wv >> 1) * 64, wc = (wv & 1) * 64;
  const int fl = l & 15, fq = l >> 4;
#pragma unroll
  for (int fr = 0; fr < 4; ++fr)
#pragma unroll
    for (int fc = 0; fc < 4; ++fc) {
      f32x4 av = acc[fr][fc];
#pragma unroll
      for (int r = 0; r < 4; ++r)
        f(m0 + wr + fr * 16 + fq * 4 + r, n0 + wc + fc * 16 + fl, av[r]);
    }
}
template<class F>
__device__ __forceinline__ void epilogue2(const f32x4 a1[4][4], const f32x4 a2[4][4], int m0, int n0, F&& f) {
  const int tid = threadIdx.x;
  const int l = tid & 63;
  const int wv = tid >> 6;
  const int wr = (wv >> 1) * 64, wc = (wv & 1) * 64;
  const int fl = l & 15, fq = l >> 4;
#pragma unroll
  for (int fr = 0; fr < 4; ++fr)
#pragma unroll
    for (int fc = 0; fc < 4; ++fc) {
      f32x4 v1 = a1[fr][fc], v2 = a2[fr][fc];
#pragma unroll
      for (int r = 0; r < 4; ++r)
        f(m0 + wr + fr * 16 + fq * 4 + r, n0 + wc + fc * 16 + fl, v1[r], v2[r]);
    }
}

// ---------------- GEMM wrapper kernels ----------------

// prc = in_proto @ pt_w^T per expert (f16x2, 4 products — LN-amplified path)
__global__ __launch_bounds__(256, 3) void k_prc(const f16* __restrict__ ip0, const f16* __restrict__ ip1,
                                                const f16* __restrict__ pt0, const f16* __restrict__ pt1,
                                                float* __restrict__ prc) {
  __shared__ f16 smem[2 * 2 * 5120];
  const int n = blockIdx.z;
  const int m0 = blockIdx.x * 128, n0 = blockIdx.y * 128;
  const size_t o = (size_t)n * MIsz;
  f32x4 acc[4][4] = {};
  mp_core<2, 2>(smem, ip0 + o, ip1 + o, pt0 + o, pt1 + o, Dd, Dd, m0, n0, Dd / 32, acc);
  float* Cp = prc + o;
  epilogue(acc, m0, n0, [&](int row, int col, float aval) {
    Cp[(size_t)row * Dd + col] = aval;
  });
}

// fused comp+mv
__global__ __launch_bounds__(256, 3) void k_fqkv(const f16* __restrict__ h0, const f16* __restrict__ h1,
                                                 const f16* __restrict__ w0, const f16* __restrict__ w1,
                                                 const f16* __restrict__ s0, const f16* __restrict__ s1,
                                                 const float* __restrict__ mu_b, const float* __restrict__ cost,
                                                 f16* __restrict__ qkvb, int C) {
  __shared__ f16 smem[5 * 5120];
  const int z = blockIdx.z, n = z / C, cb = z - n * C;
  const int m0 = blockIdx.x * 128, n0 = blockIdx.y * 128;
  const size_t ao = (size_t)cb * SDsz, bo = (size_t)n * MIsz;
  f32x4 acc1[4][4] = {}, acc2[4][4] = {};
  fused_core(smem, h0 + ao, h1 + ao, w0 + bo, w1 + bo, s0 + bo, s1 + bo,
             Dd, Dd, m0, n0, Dd / 32, acc1, acc2);
  const float* bp = mu_b + (size_t)n * Dd;
  const float* cp = cost + (size_t)n * Dd;
  f16* o0 = qkvb + ((size_t)(2 * n) * C + cb) * SDsz;
  f16* o1 = qkvb + ((size_t)(2 * n + 1) * C + cb) * SDsz;
  epilogue2(acc1, acc2, m0, n0, [&](int row, int col, float v1, float v2) {
    bool m = (v2 * SCALE_ - cp[col]) > 0.f;
    float comp = m ? silu_f(v1 + bp[col]) : 0.f;
    f16 lo, hi; split2(comp, lo, hi);
    size_t idx = (size_t)row * Dd + col;
    o0[idx] = lo; o1[idx] = hi;
  });
}

// scores = q @ k^T * scale, causal tile-skip (3 products)
__global__ __launch_bounds__(256, 3) void k_scores(const f16* __restrict__ qkvb, float* __restrict__ scores, int C) {
  const int m0 = blockIdx.x * 128, n0 = blockIdx.y * 128;
  if (n0 >= m0 + 128) return;
  __shared__ f16 smem[2 * 2 * 5120];
  const int cb = blockIdx.z;
  const f16* q0 = qkvb + ((size_t)0 * C + cb) * SDsz;
  const f16* q1 = qkvb + ((size_t)1 * C + cb) * SDsz;
  const f16* kk0 = qkvb + ((size_t)2 * C + cb) * SDsz;
  const f16* kk1 = qkvb + ((size_t)3 * C + cb) * SDsz;
  f32x4 acc[4][4] = {};
  mp_core<2, 1>(smem, q0, q1, kk0, kk1, Dd, Dd, m0, n0, Dd / 32, acc);
  float* Cp = scores + (size_t)cb * SSsz;
  epilogue(acc, m0, n0, [&](int row, int col, float aval) {
    Cp[(size_t)row * Ss + col] = aval * SCALE_;
  });
}

// attn_out = attn @ v (via vT), causal k-bound; split2 planes (3 products)
__global__ __launch_bounds__(256, 3) void k_pv(const f16* __restrict__ a0, const f16* __restrict__ a1,
                                               const f16* __restrict__ vT0, const f16* __restrict__ vT1,
                                               f16* __restrict__ ao0, f16* __restrict__ ao1) {
  __shared__ f16 smem[2 * 2 * 5120];
  const int cb = blockIdx.z;
  const int m0 = blockIdx.x * 128, n0 = blockIdx.y * 128;
  const f16* A0 = a0 + (size_t)cb * SSsz;
  const f16* A1 = a1 + (size_t)cb * SSsz;
  const f16* B0 = vT0 + (size_t)cb * SDsz;
  const f16* B1 = vT1 + (size_t)cb * SDsz;
  const int kt_end = (m0 + 128) / 32;
  f32x4 acc[4][4] = {};
  mp_core<2, 1>(smem, A0, A1, B0, B1, Ss, Ss, m0, n0, kt_end, acc);
  f16* p0 = ao0 + (size_t)cb * SDsz;
  f16* p1 = ao1 + (size_t)cb * SDsz;
  epilogue(acc, m0, n0, [&](int row, int col, float aval) {
    f16 x0, x1; split2(aval, x0, x1);
    size_t idx = (size_t)row * Dd + col;
    p0[idx] = x0; p1[idx] = x1;
  });
}

// fused co+mvo
__global__ __launch_bounds__(256, 3) void k_fout(const f16* __restrict__ ao0, const f16* __restrict__ ao1,
                                                 const f16* __restrict__ w30, const f16* __restrict__ w31,
                                                 const f16* __restrict__ s30, const f16* __restrict__ s31,
                                                 const float* __restrict__ b3, const float* __restrict__ cost3,
                                                 const float* __restrict__ x, float* __restrict__ out, int b0) {
  __shared__ f16 smem[5 * 5120];
  const int cb = blockIdx.z;
  const int m0 = blockIdx.x * 128, n0 = blockIdx.y * 128;
  const size_t ao = (size_t)cb * SDsz;
  f32x4 acc1[4][4] = {}, acc2[4][4] = {};
  fused_core(smem, ao0 + ao, ao1 + ao, w30, w31, s30, s31,
             Dd, Dd, m0, n0, Dd / 32, acc1, acc2);
  const float* xp = x + (size_t)(b0 + cb) * SDsz;
  float* op = out + (size_t)(b0 + cb) * SDsz;
  epilogue2(acc1, acc2, m0, n0, [&](int row, int col, float v1, float v2) {
    size_t idx = (size_t)row * Dd + col;
    bool m = (v2 * SCALE_ - cost3[col]) > 0.f;
    op[idx] = xp[idx] + (m ? silu_f(v1 + b3[col]) : 0.f);
  });
}

// ---------------- elementwise / small kernels ----------------
__global__ __launch_bounds__(256) void k_cost(const float* __restrict__ gate, float* __restrict__ cost) {
  int n = blockIdx.x;
  const float* g = gate + (size_t)n * Dd;
  float m = 0.f;
  for (int i = threadIdx.x; i < Dd; i += 256) m = fmaxf(m, fabsf(g[i]));
  m = block_max1(m);
  float inv = 1.0f / (m + GATE_EPS_);
  for (int i = threadIdx.x; i < Dd; i += 256) cost[(size_t)n * Dd + i] = g[i] * inv;
}

// LN(x) -> f16x2 planes for the current C-group
__global__ __launch_bounds__(256) void k_ln2(const float* __restrict__ x, const float* __restrict__ g,
                                             const float* __restrict__ b, f16* __restrict__ h0,
                                             f16* __restrict__ h1, int b0) {
  size_t row = blockIdx.x;
  const float* xr = x + ((size_t)b0 * Ss + row) * Dd;
  float4 v = ((const float4*)xr)[threadIdx.x];
  float2 s = {v.x + v.y + v.z + v.w, v.x * v.x + v.y * v.y + v.z * v.z + v.w * v.w};
  s = block_sum2(s);
  float mean = s.x * (1.0f / Dd);
  float var = s.y * (1.0f / Dd) - mean * mean;
  float rs = rsqrtf(var + LN_EPS_);
  float4 gg = ((const float4*)g)[threadIdx.x];
  float4 bb = ((const float4*)b)[threadIdx.x];
  float o[4];
  o[0] = (v.x - mean) * rs * gg.x + bb.x;
  o[1] = (v.y - mean) * rs * gg.y + bb.y;
  o[2] = (v.z - mean) * rs * gg.z + bb.z;
  o[3] = (v.w - mean) * rs * gg.w + bb.w;
  f16x4 p0, p1;
#pragma unroll
  for (int j = 0; j < 4; ++j) { f16 a_, b_; split2(o[j], a_, b_); p0[j] = a_; p1[j] = b_; }
  ((f16x4*)(h0 + row * Dd))[threadIdx.x] = p0;
  ((f16x4*)(h1 + row * Dd))[threadIdx.x] = p1;
}

// ps = proto_w + LN(prc)*pln_g + pln_b -> f16x2 planes
__global__ __launch_bounds__(256) void k_pln2(const float* __restrict__ prc, const float* __restrict__ proto_w,
                                              const float* __restrict__ pg, const float* __restrict__ pb,
                                              f16* __restrict__ s0, f16* __restrict__ s1) {
  size_t row = blockIdx.x;            // 0..4095
  int n = (int)(row >> 10);
  float4 v = ((const float4*)(prc + row * Dd))[threadIdx.x];
  float2 s = {v.x + v.y + v.z + v.w, v.x * v.x + v.y * v.y + v.z * v.z + v.w * v.w};
  s = block_sum2(s);
  float mean = s.x * (1.0f / Dd);
  float var = s.y * (1.0f / Dd) - mean * mean;
  float rs = rsqrtf(var + LN_EPS_);
  float4 gg = ((const float4*)(pg + (size_t)n * Dd))[threadIdx.x];
  float4 bb = ((const float4*)(pb + (size_t)n * Dd))[threadIdx.x];
  float4 pw = ((const float4*)(proto_w + row * Dd))[threadIdx.x];
  float o[4];
  o[0] = (v.x - mean) * rs * gg.x + bb.x + pw.x;
  o[1] = (v.y - mean) * rs * gg.y + bb.y + pw.y;
  o[2] = (v.z - mean) * rs * gg.z + bb.z + pw.z;
  o[3] = (v.w - mean) * rs * gg.w + bb.w + pw.w;
  f16x4 p0, p1;
#pragma unroll
  for (int j = 0; j < 4; ++j) { f16 a_, b_; split2(o[j], a_, b_); p0[j] = a_; p1[j] = b_; }
  ((f16x4*)(s0 + row * Dd))[threadIdx.x] = p0;
  ((f16x4*)(s1 + row * Dd))[threadIdx.x] = p1;
}

// generic f32 -> f16x2 plane split, grid-strided over float4 chunks
__global__ __launch_bounds__(256) void k_split2(const float* __restrict__ in, f16* __restrict__ p0,
                                                f16* __restrict__ p1, size_t n4) {
  size_t stride = (size_t)gridDim.x * 256;
  for (size_t i = (size_t)blockIdx.x * 256 + threadIdx.x; i < n4; i += stride) {
    float4 v = ((const float4*)in)[i];
    f16x4 lo, hi;
    f16 a_, b_;
    split2(v.x, a_, b_); lo[0] = a_; hi[0] = b_;
    split2(v.y, a_, b_); lo[1] = a_; hi[1] = b_;
    split2(v.z, a_, b_); lo[2] = a_; hi[2] = b_;
    split2(v.w, a_, b_); lo[3] = a_; hi[3] = b_;
    ((f16x4*)p0)[i] = lo;
    ((f16x4*)p1)[i] = hi;
  }
}

// transpose v planes [S][D] -> vT [D][S]
__global__ __launch_bounds__(256) void k_trans(const f16* __restrict__ qkvb, f16* __restrict__ vT0,
                                               f16* __restrict__ vT1, int C) {
  __shared__ f16 t[64][72];
  const int z = blockIdx.z, pl = z & 1, cb = z >> 1;
  const f16* in = qkvb + ((size_t)(4 + pl) * C + cb) * SDsz;
  f16* out = (pl ? vT1 : vT0) + (size_t)cb * SDsz;
  const int s0 = blockIdx.x * 64, d0 = blockIdx.y * 64;
  const int tid = threadIdx.x;
#pragma unroll
  for (int it = 0; it < 2; ++it) {
    int c = tid + it * 256;
    int r = c >> 3, c8 = (c & 7) * 8;
    *(f16x8*)&t[r][c8] = *(const f16x8*)(in + (size_t)(s0 + r) * Dd + d0 + c8);
  }
  __syncthreads();
#pragma unroll
  for (int it = 0; it < 2; ++it) {
    int c = tid + it * 256;
    int r = c >> 3, c8 = (c & 7) * 8;
    f16x8 o;
#pragma unroll
    for (int j = 0; j < 8; ++j) o[j] = t[c8 + j][r];
    *(f16x8*)(out + (size_t)(d0 + r) * Ss + s0 + c8) = o;
  }
}

// row softmax (causal) -> attn f16x2 planes
__global__ __launch_bounds__(256) void k_softmax2(const float* __restrict__ scores, f16* __restrict__ a0,
                                                  f16* __restrict__ a1) {
  const int q = blockIdx.x, cb = blockIdx.z;
  const float* row = scores + (size_t)cb * SSsz + (size_t)q * Ss;
  float4 v0 = ((const float4*)row)[threadIdx.x];
  float4 v1 = ((const float4*)row)[threadIdx.x + 256];
  int b0i = threadIdx.x * 4, b1i = (threadIdx.x + 256) * 4;
  v0.x = (b0i + 0 <= q) ? v0.x : -INFINITY;
  v0.y = (b0i + 1 <= q) ? v0.y : -INFINITY;
  v0.z = (b0i + 2 <= q) ? v0.z : -INFINITY;
  v0.w = (b0i + 3 <= q) ? v0.w : -INFINITY;
  v1.x = (b1i + 0 <= q) ? v1.x : -INFINITY;
  v1.y = (b1i + 1 <= q) ? v1.y : -INFINITY;
  v1.z = (b1i + 2 <= q) ? v1.z : -INFINITY;
  v1.w = (b1i + 3 <= q) ? v1.w : -INFINITY;
  float mx = fmaxf(fmaxf(fmaxf(v0.x, v0.y), fmaxf(v0.z, v0.w)),
                   fmaxf(fmaxf(v1.x, v1.y), fmaxf(v1.z, v1.w)));
  mx = block_max1(mx);
  v0.x = (b0i + 0 <= q) ? __expf(v0.x - mx) : 0.f;
  v0.y = (b0i + 1 <= q) ? __expf(v0.y - mx) : 0.f;
  v0.z = (b0i + 2 <= q) ? __expf(v0.z - mx) : 0.f;
  v0.w = (b0i + 3 <= q) ? __expf(v0.w - mx) : 0.f;
  v1.x = (b1i + 0 <= q) ? __expf(v1.x - mx) : 0.f;
  v1.y = (b1i + 1 <= q) ? __expf(v1.y - mx) : 0.f;
  v1.z = (b1i + 2 <= q) ? __expf(v1.z - mx) : 0.f;
  v1.w = (b1i + 3 <= q) ? __expf(v1.w - mx) : 0.f;
  float s = v0.x + v0.y + v0.z + v0.w + v1.x + v1.y + v1.z + v1.w;
  s = block_sum1(s);
  float inv = 1.0f / s;
  float p0a[4] = {v0.x * inv, v0.y * inv, v0.z * inv, v0.w * inv};
  float p1a[4] = {v1.x * inv, v1.y * inv, v1.z * inv, v1.w * inv};
  f16* r0 = a0 + (size_t)cb * SSsz + (size_t)q * Ss;
  f16* r1 = a1 + (size_t)cb * SSsz + (size_t)q * Ss;
  f16x4 lo0, hi0, lo1, hi1;
#pragma unroll
  for (int j = 0; j < 4; ++j) {
    f16 a_, b_;
    split2(p0a[j], a_, b_); lo0[j] = a_; hi0[j] = b_;
    split2(p1a[j], a_, b_); lo1[j] = a_; hi1[j] = b_;
  }
  ((f16x4*)r0)[threadIdx.x] = lo0;
  ((f16x4*)r0)[threadIdx.x + 256] = lo1;
  ((f16x4*)r1)[threadIdx.x] = hi0;
  ((f16x4*)r1)[threadIdx.x + 256] = hi1;
}

// ---------------- launch ----------------
extern "C" void kernel_launch(void* const* d_in, const int* in_sizes, int n_in,
                              void* d_out, int out_size, void* d_ws, size_t ws_size,
                              hipStream_t stream) {
  const float* x        = (const float*)d_in[0];
  const float* ln1_g    = (const float*)d_in[1];
  const float* ln1_b    = (const float*)d_in[2];
  const float* mu_w     = (const float*)d_in[3];
  const float* mu_b     = (const float*)d_in[4];
  const float* proto_w  = (const float*)d_in[5];
  const float* gate     = (const float*)d_in[6];
  const float* pt_w     = (const float*)d_in[7];
  const float* pln_g    = (const float*)d_in[8];
  const float* pln_b    = (const float*)d_in[9];
  const float* in_proto = (const float*)d_in[10];
  float* out = (float*)d_out;

  uint8_t* base = (uint8_t*)d_ws;
  size_t off = 0;
  auto take = [&](size_t b) -> uint8_t* {
    uint8_t* p = base + off;
    off = (off + b + 255) & ~(size_t)255;
    return p;
  };
  const size_t SDb = SDsz * 2;  // bytes per f16 batch-plane (4MB)
  // persistent
  f16* w0  = (f16*)take(4 * MIsz * 2);
  f16* w1  = (f16*)take(4 * MIsz * 2);
  f16* ps0 = (f16*)take(4 * MIsz * 2);
  f16* ps1 = (f16*)take(4 * MIsz * 2);
  float* cost = (float*)take(4096 * 4);
  const size_t poolOff = off;

  auto need = [&](int c) -> size_t { return poolOff + (size_t)c * 14 * SDb + (1u << 20); };
  int C = (ws_size >= need(4)) ? 4 : (ws_size >= need(2)) ? 2 : 1;

  uint8_t* pool = base + poolOff;
  // pool phase layout
  f16* h0 = (f16*)pool;
  f16* h1 = h0 + (size_t)C * SDsz;
  uint8_t* Rc = pool + (size_t)2 * C * SDb;   // 6C*SDb region
  uint8_t* Rq = Rc + (size_t)6 * C * SDb;     // 6C*SDb region
  // Rc phase A: scores f32 (4C*SDb) + vT planes (2C*SDb)
  float* scores = (float*)Rc;
  f16* vT0 = (f16*)(Rc + (size_t)C * SSsz * 4);
  f16* vT1 = vT0 + (size_t)C * SDsz;
  // Rc phase B (over scores region): ao planes
  f16* ao0 = (f16*)Rc;
  f16* ao1 = ao0 + (size_t)C * SDsz;
  // Rq: qkv planes (q0,q1,k0,k1,v0,v1), later attn planes over q/k part
  f16* qkvb = (f16*)Rq;
  f16* a0 = (f16*)Rq;
  f16* a1 = a0 + (size_t)C * SSsz;
  // prologue overlay at pool start (consumed before main loop)
  f16* ip0 = (f16*)pool;
  f16* ip1 = ip0 + 4 * MIsz;
  f16* pt0 = ip1 + 4 * MIsz;
  f16* pt1 = pt0 + 4 * MIsz;
  float* prc = (float*)(pool + 4 * (4 * MIsz * 2));

  k_cost<<<dim3(4), dim3(256), 0, stream>>>(gate, cost);
  k_split2<<<dim3(1024), dim3(256), 0, stream>>>(mu_w, w0, w1, MIsz);
  k_split2<<<dim3(1024), dim3(256), 0, stream>>>(in_proto, ip0, ip1, MIsz);
  k_split2<<<dim3(1024), dim3(256), 0, stream>>>(pt_w, pt0, pt1, MIsz);
  k_prc<<<dim3(8, 8, 4), dim3(256), 0, stream>>>(ip0, ip1, pt0, pt1, prc);
  k_pln2<<<dim3(4096), dim3(256), 0, stream>>>(prc, proto_w, pln_g, pln_b, ps0, ps1);

  for (int b0 = 0; b0 < NBATCH; b0 += C) {
    k_ln2<<<dim3(C * Ss), dim3(256), 0, stream>>>(x, ln1_g, ln1_b, h0, h1, b0);
    k_fqkv<<<dim3(16, 8, 3 * C), dim3(256), 0, stream>>>(h0, h1, w0, w1, ps0, ps1,
                                                         mu_b, cost, qkvb, C);
    k_trans<<<dim3(32, 16, 2 * C), dim3(256), 0, stream>>>(qkvb, vT0, vT1, C);
    k_scores<<<dim3(16, 16, C), dim3(256), 0, stream>>>(qkvb, scores, C);
    k_softmax2<<<dim3(Ss, 1, C), dim3(256), 0, stream>>>(scores, a0, a1);
    k_pv<<<dim3(16, 8, C), dim3(256), 0, stream>>>(a0, a1, vT0, vT1, ao0, ao1);
    k_fout<<<dim3(16, 8, C), dim3(256), 0, stream>>>(ao0, ao1,
                                                     w0 + 3 * MIsz, w1 + 3 * MIsz,
                                                     ps0 + 3 * MIsz, ps1 + 3 * MIsz,
                                                     mu_b + 3 * Dd, cost + 3 * Dd, x, out, b0);
  }
}

// Round 12
// 1239.423 us; speedup vs baseline: 1.3488x; 1.3488x over previous
//
#include <hip/hip_runtime.h>
#include <math.h>

// MoIE transformer block on MFMA via f16-split f32 emulation.
// R12: R10 structure (all-LDS staging, no reg pipelines — R11's spilled),
//      but LDS planes unpadded [128][32] with chunk XOR-swizzle
//      (c ^= (row>>1)&3) instead of +8 pad: 6 planes = 48KB -> 3 blocks/CU.
// B=4, S=2048, D=1024.
#define Dd 1024
#define Ss 2048
#define NBATCH 4
#define LDSP 4096   // f16 per plane: 128 rows x 32

static constexpr size_t SDsz = (size_t)Ss * Dd;   // 2M elems
static constexpr size_t MIsz = (size_t)Dd * Dd;   // 1M elems
static constexpr size_t SSsz = (size_t)Ss * Ss;   // 4M elems
static constexpr float LN_EPS_ = 1e-5f;
static constexpr float GATE_EPS_ = 1e-9f;
static constexpr float SCALE_ = 1.0f / 32.0f;     // 1/sqrt(1024), exact

typedef _Float16 f16;
typedef _Float16 f16x8 __attribute__((ext_vector_type(8)));
typedef _Float16 f16x4 __attribute__((ext_vector_type(4)));
typedef float f32x4 __attribute__((ext_vector_type(4)));

__device__ __forceinline__ float silu_f(float v) { return v / (1.0f + __expf(-v)); }

__device__ __forceinline__ void split2(float x, f16& a, f16& b) {
  a = (f16)x; b = (f16)(x - (float)a);
}

// swizzled chunk offset (f16 elems) for 16B chunk c of row r within a plane
__device__ __forceinline__ int swz(int r, int c) {
  return r * 32 + ((c ^ ((r >> 1) & 3)) << 3);
}

// ---------------- block reductions (256 threads = 4 waves) ----------------
__device__ __forceinline__ float2 block_sum2(float2 v) {
#pragma unroll
  for (int o = 32; o > 0; o >>= 1) { v.x += __shfl_down(v.x, o); v.y += __shfl_down(v.y, o); }
  __shared__ float2 sm2[4];
  if ((threadIdx.x & 63) == 0) sm2[threadIdx.x >> 6] = v;
  __syncthreads();
  float2 r; r.x = sm2[0].x + sm2[1].x + sm2[2].x + sm2[3].x;
  r.y = sm2[0].y + sm2[1].y + sm2[2].y + sm2[3].y;
  __syncthreads();
  return r;
}
__device__ __forceinline__ float block_sum1(float v) {
#pragma unroll
  for (int o = 32; o > 0; o >>= 1) v += __shfl_down(v, o);
  __shared__ float sm1[4];
  if ((threadIdx.x & 63) == 0) sm1[threadIdx.x >> 6] = v;
  __syncthreads();
  float r = sm1[0] + sm1[1] + sm1[2] + sm1[3];
  __syncthreads();
  return r;
}
__device__ __forceinline__ float block_max1(float v) {
#pragma unroll
  for (int o = 32; o > 0; o >>= 1) v = fmaxf(v, __shfl_down(v, o));
  __shared__ float smm[4];
  if ((threadIdx.x & 63) == 0) smm[threadIdx.x >> 6] = v;
  __syncthreads();
  float r = fmaxf(fmaxf(smm[0], smm[1]), fmaxf(smm[2], smm[3]));
  __syncthreads();
  return r;
}

// ---------------- multi-plane MFMA GEMM core (16x16x32, reg-staged) ----------------
// acc += sum_{i+j<=MAXSUM} A_i * B_j^T over K; tile 128x128, 4 waves each 64x64.
template<int PLANES, int MAXSUM>
__device__ __forceinline__ void mp_core(
    f16* __restrict__ smem,
    const f16* __restrict__ Ap0, const f16* __restrict__ Ap1,
    const f16* __restrict__ Bp0, const f16* __restrict__ Bp1,
    int lda, int ldb, int m0, int n0, int kt_end, f32x4 acc[4][4]) {
  const f16* Ap[2] = {Ap0, Ap1};
  const f16* Bp[2] = {Bp0, Bp1};
  const int tid = threadIdx.x;
  const int l = tid & 63;
  const int wv = tid >> 6;
  const int wr = (wv >> 1) * 64, wc = (wv & 1) * 64;
  const int fl = l & 15, fq = l >> 4;
  const int r0 = tid >> 2, cc = tid & 3, kc = cc * 8;

  f16x8 ra[PLANES][2], rb[PLANES][2];
#pragma unroll
  for (int p = 0; p < PLANES; ++p) {
    ra[p][0] = *(const f16x8*)(Ap[p] + (size_t)(m0 + r0) * lda + kc);
    ra[p][1] = *(const f16x8*)(Ap[p] + (size_t)(m0 + 64 + r0) * lda + kc);
    rb[p][0] = *(const f16x8*)(Bp[p] + (size_t)(n0 + r0) * ldb + kc);
    rb[p][1] = *(const f16x8*)(Bp[p] + (size_t)(n0 + 64 + r0) * ldb + kc);
  }
  for (int kt = 0; kt < kt_end; ++kt) {
    __syncthreads();
#pragma unroll
    for (int p = 0; p < PLANES; ++p) {
      *(f16x8*)(smem + p * LDSP + swz(r0, cc)) = ra[p][0];
      *(f16x8*)(smem + p * LDSP + swz(64 + r0, cc)) = ra[p][1];
      *(f16x8*)(smem + (PLANES + p) * LDSP + swz(r0, cc)) = rb[p][0];
      *(f16x8*)(smem + (PLANES + p) * LDSP + swz(64 + r0, cc)) = rb[p][1];
    }
    __syncthreads();
    if (kt + 1 < kt_end) {
      const int ko = (kt + 1) * 32 + kc;
#pragma unroll
      for (int p = 0; p < PLANES; ++p) {
        ra[p][0] = *(const f16x8*)(Ap[p] + (size_t)(m0 + r0) * lda + ko);
        ra[p][1] = *(const f16x8*)(Ap[p] + (size_t)(m0 + 64 + r0) * lda + ko);
        rb[p][0] = *(const f16x8*)(Bp[p] + (size_t)(n0 + r0) * ldb + ko);
        rb[p][1] = *(const f16x8*)(Bp[p] + (size_t)(n0 + 64 + r0) * ldb + ko);
      }
    }
    f16x8 af[PLANES][4];
#pragma unroll
    for (int p = 0; p < PLANES; ++p)
#pragma unroll
      for (int fr = 0; fr < 4; ++fr)
        af[p][fr] = *(const f16x8*)(smem + p * LDSP + swz(wr + fr * 16 + fl, fq));
#pragma unroll
    for (int fc = 0; fc < 4; ++fc) {
      f16x8 bf[PLANES];
#pragma unroll
      for (int p = 0; p < PLANES; ++p)
        bf[p] = *(const f16x8*)(smem + (PLANES + p) * LDSP + swz(wc + fc * 16 + fl, fq));
#pragma unroll
      for (int i = 0; i < PLANES; ++i)
#pragma unroll
        for (int j = 0; j < PLANES; ++j)
          if (i + j <= MAXSUM) {
#pragma unroll
            for (int fr = 0; fr < 4; ++fr)
              acc[fr][fc] = __builtin_amdgcn_mfma_f32_16x16x32_f16(af[i][fr], bf[j], acc[fr][fc], 0, 0, 0);
          }
    }
  }
}

// ---------------- fused dual-acc core (all-LDS, 6 planes, 7 products) ----------------
// LDS planes: A0,A1 (h lo/hi), W0,W1, P0,P1.
// acc1 += h@W^T   products (0,0),(0,1),(1,0)
// acc2 += h@P^T   products (0,0),(0,1),(1,0),(1,1)
__device__ __forceinline__ void fused_core(
    f16* __restrict__ smem,
    const f16* __restrict__ A0p, const f16* __restrict__ A1p,
    const f16* __restrict__ W0p, const f16* __restrict__ W1p,
    const f16* __restrict__ P0p, const f16* __restrict__ P1p,
    int lda, int ldb, int m0, int n0, int kt_end,
    f32x4 acc1[4][4], f32x4 acc2[4][4]) {
  const f16* As[2] = {A0p, A1p};
  const f16* Bs[4] = {W0p, W1p, P0p, P1p};
  const int tid = threadIdx.x;
  const int l = tid & 63;
  const int wv = tid >> 6;
  const int wr = (wv >> 1) * 64, wc = (wv & 1) * 64;
  const int fl = l & 15, fq = l >> 4;
  const int r0 = tid >> 2, cc = tid & 3, kc = cc * 8;

  f16x8 ra[2][2], rb[4][2];
#pragma unroll
  for (int p = 0; p < 2; ++p) {
    ra[p][0] = *(const f16x8*)(As[p] + (size_t)(m0 + r0) * lda + kc);
    ra[p][1] = *(const f16x8*)(As[p] + (size_t)(m0 + 64 + r0) * lda + kc);
  }
#pragma unroll
  for (int p = 0; p < 4; ++p) {
    rb[p][0] = *(const f16x8*)(Bs[p] + (size_t)(n0 + r0) * ldb + kc);
    rb[p][1] = *(const f16x8*)(Bs[p] + (size_t)(n0 + 64 + r0) * ldb + kc);
  }
  for (int kt = 0; kt < kt_end; ++kt) {
    __syncthreads();
#pragma unroll
    for (int p = 0; p < 2; ++p) {
      *(f16x8*)(smem + p * LDSP + swz(r0, cc)) = ra[p][0];
      *(f16x8*)(smem + p * LDSP + swz(64 + r0, cc)) = ra[p][1];
    }
#pragma unroll
    for (int p = 0; p < 4; ++p) {
      *(f16x8*)(smem + (2 + p) * LDSP + swz(r0, cc)) = rb[p][0];
      *(f16x8*)(smem + (2 + p) * LDSP + swz(64 + r0, cc)) = rb[p][1];
    }
    __syncthreads();
    if (kt + 1 < kt_end) {
      const int ko = (kt + 1) * 32 + kc;
#pragma unroll
      for (int p = 0; p < 2; ++p) {
        ra[p][0] = *(const f16x8*)(As[p] + (size_t)(m0 + r0) * lda + ko);
        ra[p][1] = *(const f16x8*)(As[p] + (size_t)(m0 + 64 + r0) * lda + ko);
      }
#pragma unroll
      for (int p = 0; p < 4; ++p) {
        rb[p][0] = *(const f16x8*)(Bs[p] + (size_t)(n0 + r0) * ldb + ko);
        rb[p][1] = *(const f16x8*)(Bs[p] + (size_t)(n0 + 64 + r0) * ldb + ko);
      }
    }
    f16x8 af0[4], af1[4];
#pragma unroll
    for (int fr = 0; fr < 4; ++fr) {
      af0[fr] = *(const f16x8*)(smem + 0 * LDSP + swz(wr + fr * 16 + fl, fq));
      af1[fr] = *(const f16x8*)(smem + 1 * LDSP + swz(wr + fr * 16 + fl, fq));
    }
#pragma unroll
    for (int fc = 0; fc < 4; ++fc) {
      f16x8 bw0 = *(const f16x8*)(smem + 2 * LDSP + swz(wc + fc * 16 + fl, fq));
      f16x8 bw1 = *(const f16x8*)(smem + 3 * LDSP + swz(wc + fc * 16 + fl, fq));
      f16x8 bp0 = *(const f16x8*)(smem + 4 * LDSP + swz(wc + fc * 16 + fl, fq));
      f16x8 bp1 = *(const f16x8*)(smem + 5 * LDSP + swz(wc + fc * 16 + fl, fq));
#pragma unroll
      for (int fr = 0; fr < 4; ++fr) {
        acc1[fr][fc] = __builtin_amdgcn_mfma_f32_16x16x32_f16(af0[fr], bw0, acc1[fr][fc], 0, 0, 0);
        acc2[fr][fc] = __builtin_amdgcn_mfma_f32_16x16x32_f16(af0[fr], bp0, acc2[fr][fc], 0, 0, 0);
        acc1[fr][fc] = __builtin_amdgcn_mfma_f32_16x16x32_f16(af0[fr], bw1, acc1[fr][fc], 0, 0, 0);
        acc2[fr][fc] = __builtin_amdgcn_mfma_f32_16x16x32_f16(af0[fr], bp1, acc2[fr][fc], 0, 0, 0);
        acc1[fr][fc] = __builtin_amdgcn_mfma_f32_16x16x32_f16(af1[fr], bw0, acc1[fr][fc], 0, 0, 0);
        acc2[fr][fc] = __builtin_amdgcn_mfma_f32_16x16x32_f16(af1[fr], bp0, acc2[fr][fc], 0, 0, 0);
        acc2[fr][fc] = __builtin_amdgcn_mfma_f32_16x16x32_f16(af1[fr], bp1, acc2[fr][fc], 0, 0, 0);
      }
    }
  }
}

// epilogue iterators
template<class F>
__device__ __forceinline__ void epilogue(const f32x4 acc[4][4], int m0, int n0, F&& f) {
  const int tid = threadIdx.x;
  const int l = tid & 63;
  const int wv = tid >> 6;
  const int wr = (wv >> 1) * 64, wc = (wv & 1) * 64;
  const int fl = l & 15, fq = l >> 4;
#pragma unroll
  for (int fr = 0; fr < 4; ++fr)
#pragma unroll
    for (int fc = 0; fc < 4; ++fc) {
      f32x4 av = acc[fr][fc];
#pragma unroll
      for (int r = 0; r < 4; ++r)
        f(m0 + wr + fr * 16 + fq * 4 + r, n0 + wc + fc * 16 + fl, av[r]);
    }
}
template<class F>
__device__ __forceinline__ void epilogue2(const f32x4 a1[4][4], const f32x4 a2[4][4], int m0, int n0, F&& f) {
  const int tid = threadIdx.x;
  const int l = tid & 63;
  const int wv = tid >> 6;
  const int wr = (wv >> 1) * 64, wc = (wv & 1) * 64;
  const int fl = l & 15, fq = l >> 4;
#pragma unroll
  for (int fr = 0; fr < 4; ++fr)
#pragma unroll
    for (int fc = 0; fc < 4; ++fc) {
      f32x4 v1 = a1[fr][fc], v2 = a2[fr][fc];
#pragma unroll
      for (int r = 0; r < 4; ++r)
        f(m0 + wr + fr * 16 + fq * 4 + r, n0 + wc + fc * 16 + fl, v1[r], v2[r]);
    }
}

// ---------------- GEMM wrapper kernels ----------------

// prc = in_proto @ pt_w^T per expert (f16x2, 4 products — LN-amplified path)
__global__ __launch_bounds__(256, 3) void k_prc(const f16* __restrict__ ip0, const f16* __restrict__ ip1,
                                                const f16* __restrict__ pt0, const f16* __restrict__ pt1,
                                                float* __restrict__ prc) {
  __shared__ f16 smem[4 * LDSP];
  const int n = blockIdx.z;
  const int m0 = blockIdx.x * 128, n0 = blockIdx.y * 128;
  const size_t o = (size_t)n * MIsz;
  f32x4 acc[4][4] = {};
  mp_core<2, 2>(smem, ip0 + o, ip1 + o, pt0 + o, pt1 + o, Dd, Dd, m0, n0, Dd / 32, acc);
  float* Cp = prc + o;
  epilogue(acc, m0, n0, [&](int row, int col, float aval) {
    Cp[(size_t)row * Dd + col] = aval;
  });
}

// fused comp+mv
__global__ __launch_bounds__(256, 3) void k_fqkv(const f16* __restrict__ h0, const f16* __restrict__ h1,
                                                 const f16* __restrict__ w0, const f16* __restrict__ w1,
                                                 const f16* __restrict__ s0, const f16* __restrict__ s1,
                                                 const float* __restrict__ mu_b, const float* __restrict__ cost,
                                                 f16* __restrict__ qkvb, int C) {
  __shared__ f16 smem[6 * LDSP];
  const int z = blockIdx.z, n = z / C, cb = z - n * C;
  const int m0 = blockIdx.x * 128, n0 = blockIdx.y * 128;
  const size_t ao = (size_t)cb * SDsz, bo = (size_t)n * MIsz;
  f32x4 acc1[4][4] = {}, acc2[4][4] = {};
  fused_core(smem, h0 + ao, h1 + ao, w0 + bo, w1 + bo, s0 + bo, s1 + bo,
             Dd, Dd, m0, n0, Dd / 32, acc1, acc2);
  const float* bp = mu_b + (size_t)n * Dd;
  const float* cp = cost + (size_t)n * Dd;
  f16* o0 = qkvb + ((size_t)(2 * n) * C + cb) * SDsz;
  f16* o1 = qkvb + ((size_t)(2 * n + 1) * C + cb) * SDsz;
  epilogue2(acc1, acc2, m0, n0, [&](int row, int col, float v1, float v2) {
    bool m = (v2 * SCALE_ - cp[col]) > 0.f;
    float comp = m ? silu_f(v1 + bp[col]) : 0.f;
    f16 lo, hi; split2(comp, lo, hi);
    size_t idx = (size_t)row * Dd + col;
    o0[idx] = lo; o1[idx] = hi;
  });
}

// scores = q @ k^T * scale, causal tile-skip (3 products)
__global__ __launch_bounds__(256, 3) void k_scores(const f16* __restrict__ qkvb, float* __restrict__ scores, int C) {
  const int m0 = blockIdx.x * 128, n0 = blockIdx.y * 128;
  if (n0 >= m0 + 128) return;
  __shared__ f16 smem[4 * LDSP];
  const int cb = blockIdx.z;
  const f16* q0 = qkvb + ((size_t)0 * C + cb) * SDsz;
  const f16* q1 = qkvb + ((size_t)1 * C + cb) * SDsz;
  const f16* kk0 = qkvb + ((size_t)2 * C + cb) * SDsz;
  const f16* kk1 = qkvb + ((size_t)3 * C + cb) * SDsz;
  f32x4 acc[4][4] = {};
  mp_core<2, 1>(smem, q0, q1, kk0, kk1, Dd, Dd, m0, n0, Dd / 32, acc);
  float* Cp = scores + (size_t)cb * SSsz;
  epilogue(acc, m0, n0, [&](int row, int col, float aval) {
    Cp[(size_t)row * Ss + col] = aval * SCALE_;
  });
}

// attn_out = attn @ v (via vT), causal k-bound; split2 planes (3 products)
__global__ __launch_bounds__(256, 3) void k_pv(const f16* __restrict__ a0, const f16* __restrict__ a1,
                                               const f16* __restrict__ vT0, const f16* __restrict__ vT1,
                                               f16* __restrict__ ao0, f16* __restrict__ ao1) {
  __shared__ f16 smem[4 * LDSP];
  const int cb = blockIdx.z;
  const int m0 = blockIdx.x * 128, n0 = blockIdx.y * 128;
  const f16* A0 = a0 + (size_t)cb * SSsz;
  const f16* A1 = a1 + (size_t)cb * SSsz;
  const f16* B0 = vT0 + (size_t)cb * SDsz;
  const f16* B1 = vT1 + (size_t)cb * SDsz;
  const int kt_end = (m0 + 128) / 32;
  f32x4 acc[4][4] = {};
  mp_core<2, 1>(smem, A0, A1, B0, B1, Ss, Ss, m0, n0, kt_end, acc);
  f16* p0 = ao0 + (size_t)cb * SDsz;
  f16* p1 = ao1 + (size_t)cb * SDsz;
  epilogue(acc, m0, n0, [&](int row, int col, float aval) {
    f16 x0, x1; split2(aval, x0, x1);
    size_t idx = (size_t)row * Dd + col;
    p0[idx] = x0; p1[idx] = x1;
  });
}

// fused co+mvo
__global__ __launch_bounds__(256, 3) void k_fout(const f16* __restrict__ ao0, const f16* __restrict__ ao1,
                                                 const f16* __restrict__ w30, const f16* __restrict__ w31,
                                                 const f16* __restrict__ s30, const f16* __restrict__ s31,
                                                 const float* __restrict__ b3, const float* __restrict__ cost3,
                                                 const float* __restrict__ x, float* __restrict__ out, int b0) {
  __shared__ f16 smem[6 * LDSP];
  const int cb = blockIdx.z;
  const int m0 = blockIdx.x * 128, n0 = blockIdx.y * 128;
  const size_t ao = (size_t)cb * SDsz;
  f32x4 acc1[4][4] = {}, acc2[4][4] = {};
  fused_core(smem, ao0 + ao, ao1 + ao, w30, w31, s30, s31,
             Dd, Dd, m0, n0, Dd / 32, acc1, acc2);
  const float* xp = x + (size_t)(b0 + cb) * SDsz;
  float* op = out + (size_t)(b0 + cb) * SDsz;
  epilogue2(acc1, acc2, m0, n0, [&](int row, int col, float v1, float v2) {
    size_t idx = (size_t)row * Dd + col;
    bool m = (v2 * SCALE_ - cost3[col]) > 0.f;
    op[idx] = xp[idx] + (m ? silu_f(v1 + b3[col]) : 0.f);
  });
}

// ---------------- elementwise / small kernels ----------------
__global__ __launch_bounds__(256) void k_cost(const float* __restrict__ gate, float* __restrict__ cost) {
  int n = blockIdx.x;
  const float* g = gate + (size_t)n * Dd;
  float m = 0.f;
  for (int i = threadIdx.x; i < Dd; i += 256) m = fmaxf(m, fabsf(g[i]));
  m = block_max1(m);
  float inv = 1.0f / (m + GATE_EPS_);
  for (int i = threadIdx.x; i < Dd; i += 256) cost[(size_t)n * Dd + i] = g[i] * inv;
}

// LN(x) -> f16x2 planes for the current C-group
__global__ __launch_bounds__(256) void k_ln2(const float* __restrict__ x, const float* __restrict__ g,
                                             const float* __restrict__ b, f16* __restrict__ h0,
                                             f16* __restrict__ h1, int b0) {
  size_t row = blockIdx.x;
  const float* xr = x + ((size_t)b0 * Ss + row) * Dd;
  float4 v = ((const float4*)xr)[threadIdx.x];
  float2 s = {v.x + v.y + v.z + v.w, v.x * v.x + v.y * v.y + v.z * v.z + v.w * v.w};
  s = block_sum2(s);
  float mean = s.x * (1.0f / Dd);
  float var = s.y * (1.0f / Dd) - mean * mean;
  float rs = rsqrtf(var + LN_EPS_);
  float4 gg = ((const float4*)g)[threadIdx.x];
  float4 bb = ((const float4*)b)[threadIdx.x];
  float o[4];
  o[0] = (v.x - mean) * rs * gg.x + bb.x;
  o[1] = (v.y - mean) * rs * gg.y + bb.y;
  o[2] = (v.z - mean) * rs * gg.z + bb.z;
  o[3] = (v.w - mean) * rs * gg.w + bb.w;
  f16x4 p0, p1;
#pragma unroll
  for (int j = 0; j < 4; ++j) { f16 a_, b_; split2(o[j], a_, b_); p0[j] = a_; p1[j] = b_; }
  ((f16x4*)(h0 + row * Dd))[threadIdx.x] = p0;
  ((f16x4*)(h1 + row * Dd))[threadIdx.x] = p1;
}

// ps = proto_w + LN(prc)*pln_g + pln_b -> f16x2 planes
__global__ __launch_bounds__(256) void k_pln2(const float* __restrict__ prc, const float* __restrict__ proto_w,
                                              const float* __restrict__ pg, const float* __restrict__ pb,
                                              f16* __restrict__ s0, f16* __restrict__ s1) {
  size_t row = blockIdx.x;            // 0..4095
  int n = (int)(row >> 10);
  float4 v = ((const float4*)(prc + row * Dd))[threadIdx.x];
  float2 s = {v.x + v.y + v.z + v.w, v.x * v.x + v.y * v.y + v.z * v.z + v.w * v.w};
  s = block_sum2(s);
  float mean = s.x * (1.0f / Dd);
  float var = s.y * (1.0f / Dd) - mean * mean;
  float rs = rsqrtf(var + LN_EPS_);
  float4 gg = ((const float4*)(pg + (size_t)n * Dd))[threadIdx.x];
  float4 bb = ((const float4*)(pb + (size_t)n * Dd))[threadIdx.x];
  float4 pw = ((const float4*)(proto_w + row * Dd))[threadIdx.x];
  float o[4];
  o[0] = (v.x - mean) * rs * gg.x + bb.x + pw.x;
  o[1] = (v.y - mean) * rs * gg.y + bb.y + pw.y;
  o[2] = (v.z - mean) * rs * gg.z + bb.z + pw.z;
  o[3] = (v.w - mean) * rs * gg.w + bb.w + pw.w;
  f16x4 p0, p1;
#pragma unroll
  for (int j = 0; j < 4; ++j) { f16 a_, b_; split2(o[j], a_, b_); p0[j] = a_; p1[j] = b_; }
  ((f16x4*)(s0 + row * Dd))[threadIdx.x] = p0;
  ((f16x4*)(s1 + row * Dd))[threadIdx.x] = p1;
}

// generic f32 -> f16x2 plane split, grid-strided over float4 chunks
__global__ __launch_bounds__(256) void k_split2(const float* __restrict__ in, f16* __restrict__ p0,
                                                f16* __restrict__ p1, size_t n4) {
  size_t stride = (size_t)gridDim.x * 256;
  for (size_t i = (size_t)blockIdx.x * 256 + threadIdx.x; i < n4; i += stride) {
    float4 v = ((const float4*)in)[i];
    f16x4 lo, hi;
    f16 a_, b_;
    split2(v.x, a_, b_); lo[0] = a_; hi[0] = b_;
    split2(v.y, a_, b_); lo[1] = a_; hi[1] = b_;
    split2(v.z, a_, b_); lo[2] = a_; hi[2] = b_;
    split2(v.w, a_, b_); lo[3] = a_; hi[3] = b_;
    ((f16x4*)p0)[i] = lo;
    ((f16x4*)p1)[i] = hi;
  }
}

// transpose v planes [S][D] -> vT [D][S]
__global__ __launch_bounds__(256) void k_trans(const f16* __restrict__ qkvb, f16* __restrict__ vT0,
                                               f16* __restrict__ vT1, int C) {
  __shared__ f16 t[64][72];
  const int z = blockIdx.z, pl = z & 1, cb = z >> 1;
  const f16* in = qkvb + ((size_t)(4 + pl) * C + cb) * SDsz;
  f16* out = (pl ? vT1 : vT0) + (size_t)cb * SDsz;
  const int s0 = blockIdx.x * 64, d0 = blockIdx.y * 64;
  const int tid = threadIdx.x;
#pragma unroll
  for (int it = 0; it < 2; ++it) {
    int c = tid + it * 256;
    int r = c >> 3, c8 = (c & 7) * 8;
    *(f16x8*)&t[r][c8] = *(const f16x8*)(in + (size_t)(s0 + r) * Dd + d0 + c8);
  }
  __syncthreads();
#pragma unroll
  for (int it = 0; it < 2; ++it) {
    int c = tid + it * 256;
    int r = c >> 3, c8 = (c & 7) * 8;
    f16x8 o;
#pragma unroll
    for (int j = 0; j < 8; ++j) o[j] = t[c8 + j][r];
    *(f16x8*)(out + (size_t)(d0 + r) * Ss + s0 + c8) = o;
  }
}

// row softmax (causal) -> attn f16x2 planes
__global__ __launch_bounds__(256) void k_softmax2(const float* __restrict__ scores, f16* __restrict__ a0,
                                                  f16* __restrict__ a1) {
  const int q = blockIdx.x, cb = blockIdx.z;
  const float* row = scores + (size_t)cb * SSsz + (size_t)q * Ss;
  float4 v0 = ((const float4*)row)[threadIdx.x];
  float4 v1 = ((const float4*)row)[threadIdx.x + 256];
  int b0i = threadIdx.x * 4, b1i = (threadIdx.x + 256) * 4;
  v0.x = (b0i + 0 <= q) ? v0.x : -INFINITY;
  v0.y = (b0i + 1 <= q) ? v0.y : -INFINITY;
  v0.z = (b0i + 2 <= q) ? v0.z : -INFINITY;
  v0.w = (b0i + 3 <= q) ? v0.w : -INFINITY;
  v1.x = (b1i + 0 <= q) ? v1.x : -INFINITY;
  v1.y = (b1i + 1 <= q) ? v1.y : -INFINITY;
  v1.z = (b1i + 2 <= q) ? v1.z : -INFINITY;
  v1.w = (b1i + 3 <= q) ? v1.w : -INFINITY;
  float mx = fmaxf(fmaxf(fmaxf(v0.x, v0.y), fmaxf(v0.z, v0.w)),
                   fmaxf(fmaxf(v1.x, v1.y), fmaxf(v1.z, v1.w)));
  mx = block_max1(mx);
  v0.x = (b0i + 0 <= q) ? __expf(v0.x - mx) : 0.f;
  v0.y = (b0i + 1 <= q) ? __expf(v0.y - mx) : 0.f;
  v0.z = (b0i + 2 <= q) ? __expf(v0.z - mx) : 0.f;
  v0.w = (b0i + 3 <= q) ? __expf(v0.w - mx) : 0.f;
  v1.x = (b1i + 0 <= q) ? __expf(v1.x - mx) : 0.f;
  v1.y = (b1i + 1 <= q) ? __expf(v1.y - mx) : 0.f;
  v1.z = (b1i + 2 <= q) ? __expf(v1.z - mx) : 0.f;
  v1.w = (b1i + 3 <= q) ? __expf(v1.w - mx) : 0.f;
  float s = v0.x + v0.y + v0.z + v0.w + v1.x + v1.y + v1.z + v1.w;
  s = block_sum1(s);
  float inv = 1.0f / s;
  float p0a[4] = {v0.x * inv, v0.y * inv, v0.z * inv, v0.w * inv};
  float p1a[4] = {v1.x * inv, v1.y * inv, v1.z * inv, v1.w * inv};
  f16* r0 = a0 + (size_t)cb * SSsz + (size_t)q * Ss;
  f16* r1 = a1 + (size_t)cb * SSsz + (size_t)q * Ss;
  f16x4 lo0, hi0, lo1, hi1;
#pragma unroll
  for (int j = 0; j < 4; ++j) {
    f16 a_, b_;
    split2(p0a[j], a_, b_); lo0[j] = a_; hi0[j] = b_;
    split2(p1a[j], a_, b_); lo1[j] = a_; hi1[j] = b_;
  }
  ((f16x4*)r0)[threadIdx.x] = lo0;
  ((f16x4*)r0)[threadIdx.x + 256] = lo1;
  ((f16x4*)r1)[threadIdx.x] = hi0;
  ((f16x4*)r1)[threadIdx.x + 256] = hi1;
}

// ---------------- launch ----------------
extern "C" void kernel_launch(void* const* d_in, const int* in_sizes, int n_in,
                              void* d_out, int out_size, void* d_ws, size_t ws_size,
                              hipStream_t stream) {
  const float* x        = (const float*)d_in[0];
  const float* ln1_g    = (const float*)d_in[1];
  const float* ln1_b    = (const float*)d_in[2];
  const float* mu_w     = (const float*)d_in[3];
  const float* mu_b     = (const float*)d_in[4];
  const float* proto_w  = (const float*)d_in[5];
  const float* gate     = (const float*)d_in[6];
  const float* pt_w     = (const float*)d_in[7];
  const float* pln_g    = (const float*)d_in[8];
  const float* pln_b    = (const float*)d_in[9];
  const float* in_proto = (const float*)d_in[10];
  float* out = (float*)d_out;

  uint8_t* base = (uint8_t*)d_ws;
  size_t off = 0;
  auto take = [&](size_t b) -> uint8_t* {
    uint8_t* p = base + off;
    off = (off + b + 255) & ~(size_t)255;
    return p;
  };
  const size_t SDb = SDsz * 2;  // bytes per f16 batch-plane (4MB)
  // persistent
  f16* w0  = (f16*)take(4 * MIsz * 2);
  f16* w1  = (f16*)take(4 * MIsz * 2);
  f16* ps0 = (f16*)take(4 * MIsz * 2);
  f16* ps1 = (f16*)take(4 * MIsz * 2);
  float* cost = (float*)take(4096 * 4);
  const size_t poolOff = off;

  auto need = [&](int c) -> size_t { return poolOff + (size_t)c * 14 * SDb + (1u << 20); };
  int C = (ws_size >= need(4)) ? 4 : (ws_size >= need(2)) ? 2 : 1;

  uint8_t* pool = base + poolOff;
  // pool phase layout
  f16* h0 = (f16*)pool;
  f16* h1 = h0 + (size_t)C * SDsz;
  uint8_t* Rc = pool + (size_t)2 * C * SDb;   // 6C*SDb region
  uint8_t* Rq = Rc + (size_t)6 * C * SDb;     // 6C*SDb region
  // Rc phase A: scores f32 (4C*SDb) + vT planes (2C*SDb)
  float* scores = (float*)Rc;
  f16* vT0 = (f16*)(Rc + (size_t)C * SSsz * 4);
  f16* vT1 = vT0 + (size_t)C * SDsz;
  // Rc phase B (over scores region): ao planes
  f16* ao0 = (f16*)Rc;
  f16* ao1 = ao0 + (size_t)C * SDsz;
  // Rq: qkv planes (q0,q1,k0,k1,v0,v1), later attn planes over q/k part
  f16* qkvb = (f16*)Rq;
  f16* a0 = (f16*)Rq;
  f16* a1 = a0 + (size_t)C * SSsz;
  // prologue overlay at pool start (consumed before main loop)
  f16* ip0 = (f16*)pool;
  f16* ip1 = ip0 + 4 * MIsz;
  f16* pt0 = ip1 + 4 * MIsz;
  f16* pt1 = pt0 + 4 * MIsz;
  float* prc = (float*)(pool + 4 * (4 * MIsz * 2));

  k_cost<<<dim3(4), dim3(256), 0, stream>>>(gate, cost);
  k_split2<<<dim3(1024), dim3(256), 0, stream>>>(mu_w, w0, w1, MIsz);
  k_split2<<<dim3(1024), dim3(256), 0, stream>>>(in_proto, ip0, ip1, MIsz);
  k_split2<<<dim3(1024), dim3(256), 0, stream>>>(pt_w, pt0, pt1, MIsz);
  k_prc<<<dim3(8, 8, 4), dim3(256), 0, stream>>>(ip0, ip1, pt0, pt1, prc);
  k_pln2<<<dim3(4096), dim3(256), 0, stream>>>(prc, proto_w, pln_g, pln_b, ps0, ps1);

  for (int b0 = 0; b0 < NBATCH; b0 += C) {
    k_ln2<<<dim3(C * Ss), dim3(256), 0, stream>>>(x, ln1_g, ln1_b, h0, h1, b0);
    k_fqkv<<<dim3(16, 8, 3 * C), dim3(256), 0, stream>>>(h0, h1, w0, w1, ps0, ps1,
                                                         mu_b, cost, qkvb, C);
    k_trans<<<dim3(32, 16, 2 * C), dim3(256), 0, stream>>>(qkvb, vT0, vT1, C);
    k_scores<<<dim3(16, 16, C), dim3(256), 0, stream>>>(qkvb, scores, C);
    k_softmax2<<<dim3(Ss, 1, C), dim3(256), 0, stream>>>(scores, a0, a1);
    k_pv<<<dim3(16, 8, C), dim3(256), 0, stream>>>(a0, a1, vT0, vT1, ao0, ao1);
    k_fout<<<dim3(16, 8, C), dim3(256), 0, stream>>>(ao0, ao1,
                                                     w0 + 3 * MIsz, w1 + 3 * MIsz,
                                                     ps0 + 3 * MIsz, ps1 + 3 * MIsz,
                                                     mu_b + 3 * Dd, cost + 3 * Dd, x, out, b0);
  }
}

// Round 13
// 817.811 us; speedup vs baseline: 2.0441x; 1.5155x over previous
//
#include <hip/hip_runtime.h>
#include <math.h>

// MoIE transformer block on MFMA via f16-split f32 emulation.
// R13: R12's swizzled 48KB LDS (bank-conflict-free, verified 0) but fused
//      kernels back to __launch_bounds__(256,2) — the (256,3) bound clamped
//      VGPR to 84 and caused the R11/R12 scratch spills. With 120 VGPR and
//      48KB LDS the HW can still co-schedule 3 blocks/CU.
// B=4, S=2048, D=1024.
#define Dd 1024
#define Ss 2048
#define NBATCH 4
#define LDSP 4096   // f16 per plane: 128 rows x 32

static constexpr size_t SDsz = (size_t)Ss * Dd;   // 2M elems
static constexpr size_t MIsz = (size_t)Dd * Dd;   // 1M elems
static constexpr size_t SSsz = (size_t)Ss * Ss;   // 4M elems
static constexpr float LN_EPS_ = 1e-5f;
static constexpr float GATE_EPS_ = 1e-9f;
static constexpr float SCALE_ = 1.0f / 32.0f;     // 1/sqrt(1024), exact

typedef _Float16 f16;
typedef _Float16 f16x8 __attribute__((ext_vector_type(8)));
typedef _Float16 f16x4 __attribute__((ext_vector_type(4)));
typedef float f32x4 __attribute__((ext_vector_type(4)));

__device__ __forceinline__ float silu_f(float v) { return v / (1.0f + __expf(-v)); }

__device__ __forceinline__ void split2(float x, f16& a, f16& b) {
  a = (f16)x; b = (f16)(x - (float)a);
}

// swizzled chunk offset (f16 elems) for 16B chunk c of row r within a plane
__device__ __forceinline__ int swz(int r, int c) {
  return r * 32 + ((c ^ ((r >> 1) & 3)) << 3);
}

// ---------------- block reductions (256 threads = 4 waves) ----------------
__device__ __forceinline__ float2 block_sum2(float2 v) {
#pragma unroll
  for (int o = 32; o > 0; o >>= 1) { v.x += __shfl_down(v.x, o); v.y += __shfl_down(v.y, o); }
  __shared__ float2 sm2[4];
  if ((threadIdx.x & 63) == 0) sm2[threadIdx.x >> 6] = v;
  __syncthreads();
  float2 r; r.x = sm2[0].x + sm2[1].x + sm2[2].x + sm2[3].x;
  r.y = sm2[0].y + sm2[1].y + sm2[2].y + sm2[3].y;
  __syncthreads();
  return r;
}
__device__ __forceinline__ float block_sum1(float v) {
#pragma unroll
  for (int o = 32; o > 0; o >>= 1) v += __shfl_down(v, o);
  __shared__ float sm1[4];
  if ((threadIdx.x & 63) == 0) sm1[threadIdx.x >> 6] = v;
  __syncthreads();
  float r = sm1[0] + sm1[1] + sm1[2] + sm1[3];
  __syncthreads();
  return r;
}
__device__ __forceinline__ float block_max1(float v) {
#pragma unroll
  for (int o = 32; o > 0; o >>= 1) v = fmaxf(v, __shfl_down(v, o));
  __shared__ float smm[4];
  if ((threadIdx.x & 63) == 0) smm[threadIdx.x >> 6] = v;
  __syncthreads();
  float r = fmaxf(fmaxf(smm[0], smm[1]), fmaxf(smm[2], smm[3]));
  __syncthreads();
  return r;
}

// ---------------- multi-plane MFMA GEMM core (16x16x32, reg-staged) ----------------
// acc += sum_{i+j<=MAXSUM} A_i * B_j^T over K; tile 128x128, 4 waves each 64x64.
template<int PLANES, int MAXSUM>
__device__ __forceinline__ void mp_core(
    f16* __restrict__ smem,
    const f16* __restrict__ Ap0, const f16* __restrict__ Ap1,
    const f16* __restrict__ Bp0, const f16* __restrict__ Bp1,
    int lda, int ldb, int m0, int n0, int kt_end, f32x4 acc[4][4]) {
  const f16* Ap[2] = {Ap0, Ap1};
  const f16* Bp[2] = {Bp0, Bp1};
  const int tid = threadIdx.x;
  const int l = tid & 63;
  const int wv = tid >> 6;
  const int wr = (wv >> 1) * 64, wc = (wv & 1) * 64;
  const int fl = l & 15, fq = l >> 4;
  const int r0 = tid >> 2, cc = tid & 3, kc = cc * 8;

  f16x8 ra[PLANES][2], rb[PLANES][2];
#pragma unroll
  for (int p = 0; p < PLANES; ++p) {
    ra[p][0] = *(const f16x8*)(Ap[p] + (size_t)(m0 + r0) * lda + kc);
    ra[p][1] = *(const f16x8*)(Ap[p] + (size_t)(m0 + 64 + r0) * lda + kc);
    rb[p][0] = *(const f16x8*)(Bp[p] + (size_t)(n0 + r0) * ldb + kc);
    rb[p][1] = *(const f16x8*)(Bp[p] + (size_t)(n0 + 64 + r0) * ldb + kc);
  }
  for (int kt = 0; kt < kt_end; ++kt) {
    __syncthreads();
#pragma unroll
    for (int p = 0; p < PLANES; ++p) {
      *(f16x8*)(smem + p * LDSP + swz(r0, cc)) = ra[p][0];
      *(f16x8*)(smem + p * LDSP + swz(64 + r0, cc)) = ra[p][1];
      *(f16x8*)(smem + (PLANES + p) * LDSP + swz(r0, cc)) = rb[p][0];
      *(f16x8*)(smem + (PLANES + p) * LDSP + swz(64 + r0, cc)) = rb[p][1];
    }
    __syncthreads();
    if (kt + 1 < kt_end) {
      const int ko = (kt + 1) * 32 + kc;
#pragma unroll
      for (int p = 0; p < PLANES; ++p) {
        ra[p][0] = *(const f16x8*)(Ap[p] + (size_t)(m0 + r0) * lda + ko);
        ra[p][1] = *(const f16x8*)(Ap[p] + (size_t)(m0 + 64 + r0) * lda + ko);
        rb[p][0] = *(const f16x8*)(Bp[p] + (size_t)(n0 + r0) * ldb + ko);
        rb[p][1] = *(const f16x8*)(Bp[p] + (size_t)(n0 + 64 + r0) * ldb + ko);
      }
    }
    f16x8 af[PLANES][4];
#pragma unroll
    for (int p = 0; p < PLANES; ++p)
#pragma unroll
      for (int fr = 0; fr < 4; ++fr)
        af[p][fr] = *(const f16x8*)(smem + p * LDSP + swz(wr + fr * 16 + fl, fq));
#pragma unroll
    for (int fc = 0; fc < 4; ++fc) {
      f16x8 bf[PLANES];
#pragma unroll
      for (int p = 0; p < PLANES; ++p)
        bf[p] = *(const f16x8*)(smem + (PLANES + p) * LDSP + swz(wc + fc * 16 + fl, fq));
#pragma unroll
      for (int i = 0; i < PLANES; ++i)
#pragma unroll
        for (int j = 0; j < PLANES; ++j)
          if (i + j <= MAXSUM) {
#pragma unroll
            for (int fr = 0; fr < 4; ++fr)
              acc[fr][fc] = __builtin_amdgcn_mfma_f32_16x16x32_f16(af[i][fr], bf[j], acc[fr][fc], 0, 0, 0);
          }
    }
  }
}

// ---------------- fused dual-acc core (all-LDS, 6 planes, 7 products) ----------------
// LDS planes: A0,A1 (h lo/hi), W0,W1, P0,P1.
// acc1 += h@W^T   products (0,0),(0,1),(1,0)
// acc2 += h@P^T   products (0,0),(0,1),(1,0),(1,1)
__device__ __forceinline__ void fused_core(
    f16* __restrict__ smem,
    const f16* __restrict__ A0p, const f16* __restrict__ A1p,
    const f16* __restrict__ W0p, const f16* __restrict__ W1p,
    const f16* __restrict__ P0p, const f16* __restrict__ P1p,
    int lda, int ldb, int m0, int n0, int kt_end,
    f32x4 acc1[4][4], f32x4 acc2[4][4]) {
  const f16* As[2] = {A0p, A1p};
  const f16* Bs[4] = {W0p, W1p, P0p, P1p};
  const int tid = threadIdx.x;
  const int l = tid & 63;
  const int wv = tid >> 6;
  const int wr = (wv >> 1) * 64, wc = (wv & 1) * 64;
  const int fl = l & 15, fq = l >> 4;
  const int r0 = tid >> 2, cc = tid & 3, kc = cc * 8;

  f16x8 ra[2][2], rb[4][2];
#pragma unroll
  for (int p = 0; p < 2; ++p) {
    ra[p][0] = *(const f16x8*)(As[p] + (size_t)(m0 + r0) * lda + kc);
    ra[p][1] = *(const f16x8*)(As[p] + (size_t)(m0 + 64 + r0) * lda + kc);
  }
#pragma unroll
  for (int p = 0; p < 4; ++p) {
    rb[p][0] = *(const f16x8*)(Bs[p] + (size_t)(n0 + r0) * ldb + kc);
    rb[p][1] = *(const f16x8*)(Bs[p] + (size_t)(n0 + 64 + r0) * ldb + kc);
  }
  for (int kt = 0; kt < kt_end; ++kt) {
    __syncthreads();
#pragma unroll
    for (int p = 0; p < 2; ++p) {
      *(f16x8*)(smem + p * LDSP + swz(r0, cc)) = ra[p][0];
      *(f16x8*)(smem + p * LDSP + swz(64 + r0, cc)) = ra[p][1];
    }
#pragma unroll
    for (int p = 0; p < 4; ++p) {
      *(f16x8*)(smem + (2 + p) * LDSP + swz(r0, cc)) = rb[p][0];
      *(f16x8*)(smem + (2 + p) * LDSP + swz(64 + r0, cc)) = rb[p][1];
    }
    __syncthreads();
    if (kt + 1 < kt_end) {
      const int ko = (kt + 1) * 32 + kc;
#pragma unroll
      for (int p = 0; p < 2; ++p) {
        ra[p][0] = *(const f16x8*)(As[p] + (size_t)(m0 + r0) * lda + ko);
        ra[p][1] = *(const f16x8*)(As[p] + (size_t)(m0 + 64 + r0) * lda + ko);
      }
#pragma unroll
      for (int p = 0; p < 4; ++p) {
        rb[p][0] = *(const f16x8*)(Bs[p] + (size_t)(n0 + r0) * ldb + ko);
        rb[p][1] = *(const f16x8*)(Bs[p] + (size_t)(n0 + 64 + r0) * ldb + ko);
      }
    }
    f16x8 af0[4], af1[4];
#pragma unroll
    for (int fr = 0; fr < 4; ++fr) {
      af0[fr] = *(const f16x8*)(smem + 0 * LDSP + swz(wr + fr * 16 + fl, fq));
      af1[fr] = *(const f16x8*)(smem + 1 * LDSP + swz(wr + fr * 16 + fl, fq));
    }
#pragma unroll
    for (int fc = 0; fc < 4; ++fc) {
      f16x8 bw0 = *(const f16x8*)(smem + 2 * LDSP + swz(wc + fc * 16 + fl, fq));
      f16x8 bw1 = *(const f16x8*)(smem + 3 * LDSP + swz(wc + fc * 16 + fl, fq));
      f16x8 bp0 = *(const f16x8*)(smem + 4 * LDSP + swz(wc + fc * 16 + fl, fq));
      f16x8 bp1 = *(const f16x8*)(smem + 5 * LDSP + swz(wc + fc * 16 + fl, fq));
#pragma unroll
      for (int fr = 0; fr < 4; ++fr) {
        acc1[fr][fc] = __builtin_amdgcn_mfma_f32_16x16x32_f16(af0[fr], bw0, acc1[fr][fc], 0, 0, 0);
        acc2[fr][fc] = __builtin_amdgcn_mfma_f32_16x16x32_f16(af0[fr], bp0, acc2[fr][fc], 0, 0, 0);
        acc1[fr][fc] = __builtin_amdgcn_mfma_f32_16x16x32_f16(af0[fr], bw1, acc1[fr][fc], 0, 0, 0);
        acc2[fr][fc] = __builtin_amdgcn_mfma_f32_16x16x32_f16(af0[fr], bp1, acc2[fr][fc], 0, 0, 0);
        acc1[fr][fc] = __builtin_amdgcn_mfma_f32_16x16x32_f16(af1[fr], bw0, acc1[fr][fc], 0, 0, 0);
        acc2[fr][fc] = __builtin_amdgcn_mfma_f32_16x16x32_f16(af1[fr], bp0, acc2[fr][fc], 0, 0, 0);
        acc2[fr][fc] = __builtin_amdgcn_mfma_f32_16x16x32_f16(af1[fr], bp1, acc2[fr][fc], 0, 0, 0);
      }
    }
  }
}

// epilogue iterators
template<class F>
__device__ __forceinline__ void epilogue(const f32x4 acc[4][4], int m0, int n0, F&& f) {
  const int tid = threadIdx.x;
  const int l = tid & 63;
  const int wv = tid >> 6;
  const int wr = (wv >> 1) * 64, wc = (wv & 1) * 64;
  const int fl = l & 15, fq = l >> 4;
#pragma unroll
  for (int fr = 0; fr < 4; ++fr)
#pragma unroll
    for (int fc = 0; fc < 4; ++fc) {
      f32x4 av = acc[fr][fc];
#pragma unroll
      for (int r = 0; r < 4; ++r)
        f(m0 + wr + fr * 16 + fq * 4 + r, n0 + wc + fc * 16 + fl, av[r]);
    }
}
template<class F>
__device__ __forceinline__ void epilogue2(const f32x4 a1[4][4], const f32x4 a2[4][4], int m0, int n0, F&& f) {
  const int tid = threadIdx.x;
  const int l = tid & 63;
  const int wv = tid >> 6;
  const int wr = (wv >> 1) * 64, wc = (wv & 1) * 64;
  const int fl = l & 15, fq = l >> 4;
#pragma unroll
  for (int fr = 0; fr < 4; ++fr)
#pragma unroll
    for (int fc = 0; fc < 4; ++fc) {
      f32x4 v1 = a1[fr][fc], v2 = a2[fr][fc];
#pragma unroll
      for (int r = 0; r < 4; ++r)
        f(m0 + wr + fr * 16 + fq * 4 + r, n0 + wc + fc * 16 + fl, v1[r], v2[r]);
    }
}

// ---------------- GEMM wrapper kernels ----------------

// prc = in_proto @ pt_w^T per expert (f16x2, 4 products — LN-amplified path)
__global__ __launch_bounds__(256, 3) void k_prc(const f16* __restrict__ ip0, const f16* __restrict__ ip1,
                                                const f16* __restrict__ pt0, const f16* __restrict__ pt1,
                                                float* __restrict__ prc) {
  __shared__ f16 smem[4 * LDSP];
  const int n = blockIdx.z;
  const int m0 = blockIdx.x * 128, n0 = blockIdx.y * 128;
  const size_t o = (size_t)n * MIsz;
  f32x4 acc[4][4] = {};
  mp_core<2, 2>(smem, ip0 + o, ip1 + o, pt0 + o, pt1 + o, Dd, Dd, m0, n0, Dd / 32, acc);
  float* Cp = prc + o;
  epilogue(acc, m0, n0, [&](int row, int col, float aval) {
    Cp[(size_t)row * Dd + col] = aval;
  });
}

// fused comp+mv
__global__ __launch_bounds__(256, 2) void k_fqkv(const f16* __restrict__ h0, const f16* __restrict__ h1,
                                                 const f16* __restrict__ w0, const f16* __restrict__ w1,
                                                 const f16* __restrict__ s0, const f16* __restrict__ s1,
                                                 const float* __restrict__ mu_b, const float* __restrict__ cost,
                                                 f16* __restrict__ qkvb, int C) {
  __shared__ f16 smem[6 * LDSP];
  const int z = blockIdx.z, n = z / C, cb = z - n * C;
  const int m0 = blockIdx.x * 128, n0 = blockIdx.y * 128;
  const size_t ao = (size_t)cb * SDsz, bo = (size_t)n * MIsz;
  f32x4 acc1[4][4] = {}, acc2[4][4] = {};
  fused_core(smem, h0 + ao, h1 + ao, w0 + bo, w1 + bo, s0 + bo, s1 + bo,
             Dd, Dd, m0, n0, Dd / 32, acc1, acc2);
  const float* bp = mu_b + (size_t)n * Dd;
  const float* cp = cost + (size_t)n * Dd;
  f16* o0 = qkvb + ((size_t)(2 * n) * C + cb) * SDsz;
  f16* o1 = qkvb + ((size_t)(2 * n + 1) * C + cb) * SDsz;
  epilogue2(acc1, acc2, m0, n0, [&](int row, int col, float v1, float v2) {
    bool m = (v2 * SCALE_ - cp[col]) > 0.f;
    float comp = m ? silu_f(v1 + bp[col]) : 0.f;
    f16 lo, hi; split2(comp, lo, hi);
    size_t idx = (size_t)row * Dd + col;
    o0[idx] = lo; o1[idx] = hi;
  });
}

// scores = q @ k^T * scale, causal tile-skip (3 products)
__global__ __launch_bounds__(256, 3) void k_scores(const f16* __restrict__ qkvb, float* __restrict__ scores, int C) {
  const int m0 = blockIdx.x * 128, n0 = blockIdx.y * 128;
  if (n0 >= m0 + 128) return;
  __shared__ f16 smem[4 * LDSP];
  const int cb = blockIdx.z;
  const f16* q0 = qkvb + ((size_t)0 * C + cb) * SDsz;
  const f16* q1 = qkvb + ((size_t)1 * C + cb) * SDsz;
  const f16* kk0 = qkvb + ((size_t)2 * C + cb) * SDsz;
  const f16* kk1 = qkvb + ((size_t)3 * C + cb) * SDsz;
  f32x4 acc[4][4] = {};
  mp_core<2, 1>(smem, q0, q1, kk0, kk1, Dd, Dd, m0, n0, Dd / 32, acc);
  float* Cp = scores + (size_t)cb * SSsz;
  epilogue(acc, m0, n0, [&](int row, int col, float aval) {
    Cp[(size_t)row * Ss + col] = aval * SCALE_;
  });
}

// attn_out = attn @ v (via vT), causal k-bound; split2 planes (3 products)
__global__ __launch_bounds__(256, 3) void k_pv(const f16* __restrict__ a0, const f16* __restrict__ a1,
                                               const f16* __restrict__ vT0, const f16* __restrict__ vT1,
                                               f16* __restrict__ ao0, f16* __restrict__ ao1) {
  __shared__ f16 smem[4 * LDSP];
  const int cb = blockIdx.z;
  const int m0 = blockIdx.x * 128, n0 = blockIdx.y * 128;
  const f16* A0 = a0 + (size_t)cb * SSsz;
  const f16* A1 = a1 + (size_t)cb * SSsz;
  const f16* B0 = vT0 + (size_t)cb * SDsz;
  const f16* B1 = vT1 + (size_t)cb * SDsz;
  const int kt_end = (m0 + 128) / 32;
  f32x4 acc[4][4] = {};
  mp_core<2, 1>(smem, A0, A1, B0, B1, Ss, Ss, m0, n0, kt_end, acc);
  f16* p0 = ao0 + (size_t)cb * SDsz;
  f16* p1 = ao1 + (size_t)cb * SDsz;
  epilogue(acc, m0, n0, [&](int row, int col, float aval) {
    f16 x0, x1; split2(aval, x0, x1);
    size_t idx = (size_t)row * Dd + col;
    p0[idx] = x0; p1[idx] = x1;
  });
}

// fused co+mvo
__global__ __launch_bounds__(256, 2) void k_fout(const f16* __restrict__ ao0, const f16* __restrict__ ao1,
                                                 const f16* __restrict__ w30, const f16* __restrict__ w31,
                                                 const f16* __restrict__ s30, const f16* __restrict__ s31,
                                                 const float* __restrict__ b3, const float* __restrict__ cost3,
                                                 const float* __restrict__ x, float* __restrict__ out, int b0) {
  __shared__ f16 smem[6 * LDSP];
  const int cb = blockIdx.z;
  const int m0 = blockIdx.x * 128, n0 = blockIdx.y * 128;
  const size_t ao = (size_t)cb * SDsz;
  f32x4 acc1[4][4] = {}, acc2[4][4] = {};
  fused_core(smem, ao0 + ao, ao1 + ao, w30, w31, s30, s31,
             Dd, Dd, m0, n0, Dd / 32, acc1, acc2);
  const float* xp = x + (size_t)(b0 + cb) * SDsz;
  float* op = out + (size_t)(b0 + cb) * SDsz;
  epilogue2(acc1, acc2, m0, n0, [&](int row, int col, float v1, float v2) {
    size_t idx = (size_t)row * Dd + col;
    bool m = (v2 * SCALE_ - cost3[col]) > 0.f;
    op[idx] = xp[idx] + (m ? silu_f(v1 + b3[col]) : 0.f);
  });
}

// ---------------- elementwise / small kernels ----------------
__global__ __launch_bounds__(256) void k_cost(const float* __restrict__ gate, float* __restrict__ cost) {
  int n = blockIdx.x;
  const float* g = gate + (size_t)n * Dd;
  float m = 0.f;
  for (int i = threadIdx.x; i < Dd; i += 256) m = fmaxf(m, fabsf(g[i]));
  m = block_max1(m);
  float inv = 1.0f / (m + GATE_EPS_);
  for (int i = threadIdx.x; i < Dd; i += 256) cost[(size_t)n * Dd + i] = g[i] * inv;
}

// LN(x) -> f16x2 planes for the current C-group
__global__ __launch_bounds__(256) void k_ln2(const float* __restrict__ x, const float* __restrict__ g,
                                             const float* __restrict__ b, f16* __restrict__ h0,
                                             f16* __restrict__ h1, int b0) {
  size_t row = blockIdx.x;
  const float* xr = x + ((size_t)b0 * Ss + row) * Dd;
  float4 v = ((const float4*)xr)[threadIdx.x];
  float2 s = {v.x + v.y + v.z + v.w, v.x * v.x + v.y * v.y + v.z * v.z + v.w * v.w};
  s = block_sum2(s);
  float mean = s.x * (1.0f / Dd);
  float var = s.y * (1.0f / Dd) - mean * mean;
  float rs = rsqrtf(var + LN_EPS_);
  float4 gg = ((const float4*)g)[threadIdx.x];
  float4 bb = ((const float4*)b)[threadIdx.x];
  float o[4];
  o[0] = (v.x - mean) * rs * gg.x + bb.x;
  o[1] = (v.y - mean) * rs * gg.y + bb.y;
  o[2] = (v.z - mean) * rs * gg.z + bb.z;
  o[3] = (v.w - mean) * rs * gg.w + bb.w;
  f16x4 p0, p1;
#pragma unroll
  for (int j = 0; j < 4; ++j) { f16 a_, b_; split2(o[j], a_, b_); p0[j] = a_; p1[j] = b_; }
  ((f16x4*)(h0 + row * Dd))[threadIdx.x] = p0;
  ((f16x4*)(h1 + row * Dd))[threadIdx.x] = p1;
}

// ps = proto_w + LN(prc)*pln_g + pln_b -> f16x2 planes
__global__ __launch_bounds__(256) void k_pln2(const float* __restrict__ prc, const float* __restrict__ proto_w,
                                              const float* __restrict__ pg, const float* __restrict__ pb,
                                              f16* __restrict__ s0, f16* __restrict__ s1) {
  size_t row = blockIdx.x;            // 0..4095
  int n = (int)(row >> 10);
  float4 v = ((const float4*)(prc + row * Dd))[threadIdx.x];
  float2 s = {v.x + v.y + v.z + v.w, v.x * v.x + v.y * v.y + v.z * v.z + v.w * v.w};
  s = block_sum2(s);
  float mean = s.x * (1.0f / Dd);
  float var = s.y * (1.0f / Dd) - mean * mean;
  float rs = rsqrtf(var + LN_EPS_);
  float4 gg = ((const float4*)(pg + (size_t)n * Dd))[threadIdx.x];
  float4 bb = ((const float4*)(pb + (size_t)n * Dd))[threadIdx.x];
  float4 pw = ((const float4*)(proto_w + row * Dd))[threadIdx.x];
  float o[4];
  o[0] = (v.x - mean) * rs * gg.x + bb.x + pw.x;
  o[1] = (v.y - mean) * rs * gg.y + bb.y + pw.y;
  o[2] = (v.z - mean) * rs * gg.z + bb.z + pw.z;
  o[3] = (v.w - mean) * rs * gg.w + bb.w + pw.w;
  f16x4 p0, p1;
#pragma unroll
  for (int j = 0; j < 4; ++j) { f16 a_, b_; split2(o[j], a_, b_); p0[j] = a_; p1[j] = b_; }
  ((f16x4*)(s0 + row * Dd))[threadIdx.x] = p0;
  ((f16x4*)(s1 + row * Dd))[threadIdx.x] = p1;
}

// generic f32 -> f16x2 plane split, grid-strided over float4 chunks
__global__ __launch_bounds__(256) void k_split2(const float* __restrict__ in, f16* __restrict__ p0,
                                                f16* __restrict__ p1, size_t n4) {
  size_t stride = (size_t)gridDim.x * 256;
  for (size_t i = (size_t)blockIdx.x * 256 + threadIdx.x; i < n4; i += stride) {
    float4 v = ((const float4*)in)[i];
    f16x4 lo, hi;
    f16 a_, b_;
    split2(v.x, a_, b_); lo[0] = a_; hi[0] = b_;
    split2(v.y, a_, b_); lo[1] = a_; hi[1] = b_;
    split2(v.z, a_, b_); lo[2] = a_; hi[2] = b_;
    split2(v.w, a_, b_); lo[3] = a_; hi[3] = b_;
    ((f16x4*)p0)[i] = lo;
    ((f16x4*)p1)[i] = hi;
  }
}

// transpose v planes [S][D] -> vT [D][S]
__global__ __launch_bounds__(256) void k_trans(const f16* __restrict__ qkvb, f16* __restrict__ vT0,
                                               f16* __restrict__ vT1, int C) {
  __shared__ f16 t[64][72];
  const int z = blockIdx.z, pl = z & 1, cb = z >> 1;
  const f16* in = qkvb + ((size_t)(4 + pl) * C + cb) * SDsz;
  f16* out = (pl ? vT1 : vT0) + (size_t)cb * SDsz;
  const int s0 = blockIdx.x * 64, d0 = blockIdx.y * 64;
  const int tid = threadIdx.x;
#pragma unroll
  for (int it = 0; it < 2; ++it) {
    int c = tid + it * 256;
    int r = c >> 3, c8 = (c & 7) * 8;
    *(f16x8*)&t[r][c8] = *(const f16x8*)(in + (size_t)(s0 + r) * Dd + d0 + c8);
  }
  __syncthreads();
#pragma unroll
  for (int it = 0; it < 2; ++it) {
    int c = tid + it * 256;
    int r = c >> 3, c8 = (c & 7) * 8;
    f16x8 o;
#pragma unroll
    for (int j = 0; j < 8; ++j) o[j] = t[c8 + j][r];
    *(f16x8*)(out + (size_t)(d0 + r) * Ss + s0 + c8) = o;
  }
}

// row softmax (causal) -> attn f16x2 planes
__global__ __launch_bounds__(256) void k_softmax2(const float* __restrict__ scores, f16* __restrict__ a0,
                                                  f16* __restrict__ a1) {
  const int q = blockIdx.x, cb = blockIdx.z;
  const float* row = scores + (size_t)cb * SSsz + (size_t)q * Ss;
  float4 v0 = ((const float4*)row)[threadIdx.x];
  float4 v1 = ((const float4*)row)[threadIdx.x + 256];
  int b0i = threadIdx.x * 4, b1i = (threadIdx.x + 256) * 4;
  v0.x = (b0i + 0 <= q) ? v0.x : -INFINITY;
  v0.y = (b0i + 1 <= q) ? v0.y : -INFINITY;
  v0.z = (b0i + 2 <= q) ? v0.z : -INFINITY;
  v0.w = (b0i + 3 <= q) ? v0.w : -INFINITY;
  v1.x = (b1i + 0 <= q) ? v1.x : -INFINITY;
  v1.y = (b1i + 1 <= q) ? v1.y : -INFINITY;
  v1.z = (b1i + 2 <= q) ? v1.z : -INFINITY;
  v1.w = (b1i + 3 <= q) ? v1.w : -INFINITY;
  float mx = fmaxf(fmaxf(fmaxf(v0.x, v0.y), fmaxf(v0.z, v0.w)),
                   fmaxf(fmaxf(v1.x, v1.y), fmaxf(v1.z, v1.w)));
  mx = block_max1(mx);
  v0.x = (b0i + 0 <= q) ? __expf(v0.x - mx) : 0.f;
  v0.y = (b0i + 1 <= q) ? __expf(v0.y - mx) : 0.f;
  v0.z = (b0i + 2 <= q) ? __expf(v0.z - mx) : 0.f;
  v0.w = (b0i + 3 <= q) ? __expf(v0.w - mx) : 0.f;
  v1.x = (b1i + 0 <= q) ? __expf(v1.x - mx) : 0.f;
  v1.y = (b1i + 1 <= q) ? __expf(v1.y - mx) : 0.f;
  v1.z = (b1i + 2 <= q) ? __expf(v1.z - mx) : 0.f;
  v1.w = (b1i + 3 <= q) ? __expf(v1.w - mx) : 0.f;
  float s = v0.x + v0.y + v0.z + v0.w + v1.x + v1.y + v1.z + v1.w;
  s = block_sum1(s);
  float inv = 1.0f / s;
  float p0a[4] = {v0.x * inv, v0.y * inv, v0.z * inv, v0.w * inv};
  float p1a[4] = {v1.x * inv, v1.y * inv, v1.z * inv, v1.w * inv};
  f16* r0 = a0 + (size_t)cb * SSsz + (size_t)q * Ss;
  f16* r1 = a1 + (size_t)cb * SSsz + (size_t)q * Ss;
  f16x4 lo0, hi0, lo1, hi1;
#pragma unroll
  for (int j = 0; j < 4; ++j) {
    f16 a_, b_;
    split2(p0a[j], a_, b_); lo0[j] = a_; hi0[j] = b_;
    split2(p1a[j], a_, b_); lo1[j] = a_; hi1[j] = b_;
  }
  ((f16x4*)r0)[threadIdx.x] = lo0;
  ((f16x4*)r0)[threadIdx.x + 256] = lo1;
  ((f16x4*)r1)[threadIdx.x] = hi0;
  ((f16x4*)r1)[threadIdx.x + 256] = hi1;
}

// ---------------- launch ----------------
extern "C" void kernel_launch(void* const* d_in, const int* in_sizes, int n_in,
                              void* d_out, int out_size, void* d_ws, size_t ws_size,
                              hipStream_t stream) {
  const float* x        = (const float*)d_in[0];
  const float* ln1_g    = (const float*)d_in[1];
  const float* ln1_b    = (const float*)d_in[2];
  const float* mu_w     = (const float*)d_in[3];
  const float* mu_b     = (const float*)d_in[4];
  const float* proto_w  = (const float*)d_in[5];
  const float* gate     = (const float*)d_in[6];
  const float* pt_w     = (const float*)d_in[7];
  const float* pln_g    = (const float*)d_in[8];
  const float* pln_b    = (const float*)d_in[9];
  const float* in_proto = (const float*)d_in[10];
  float* out = (float*)d_out;

  uint8_t* base = (uint8_t*)d_ws;
  size_t off = 0;
  auto take = [&](size_t b) -> uint8_t* {
    uint8_t* p = base + off;
    off = (off + b + 255) & ~(size_t)255;
    return p;
  };
  const size_t SDb = SDsz * 2;  // bytes per f16 batch-plane (4MB)
  // persistent
  f16* w0  = (f16*)take(4 * MIsz * 2);
  f16* w1  = (f16*)take(4 * MIsz * 2);
  f16* ps0 = (f16*)take(4 * MIsz * 2);
  f16* ps1 = (f16*)take(4 * MIsz * 2);
  float* cost = (float*)take(4096 * 4);
  const size_t poolOff = off;

  auto need = [&](int c) -> size_t { return poolOff + (size_t)c * 14 * SDb + (1u << 20); };
  int C = (ws_size >= need(4)) ? 4 : (ws_size >= need(2)) ? 2 : 1;

  uint8_t* pool = base + poolOff;
  // pool phase layout
  f16* h0 = (f16*)pool;
  f16* h1 = h0 + (size_t)C * SDsz;
  uint8_t* Rc = pool + (size_t)2 * C * SDb;   // 6C*SDb region
  uint8_t* Rq = Rc + (size_t)6 * C * SDb;     // 6C*SDb region
  // Rc phase A: scores f32 (4C*SDb) + vT planes (2C*SDb)
  float* scores = (float*)Rc;
  f16* vT0 = (f16*)(Rc + (size_t)C * SSsz * 4);
  f16* vT1 = vT0 + (size_t)C * SDsz;
  // Rc phase B (over scores region): ao planes
  f16* ao0 = (f16*)Rc;
  f16* ao1 = ao0 + (size_t)C * SDsz;
  // Rq: qkv planes (q0,q1,k0,k1,v0,v1), later attn planes over q/k part
  f16* qkvb = (f16*)Rq;
  f16* a0 = (f16*)Rq;
  f16* a1 = a0 + (size_t)C * SSsz;
  // prologue overlay at pool start (consumed before main loop)
  f16* ip0 = (f16*)pool;
  f16* ip1 = ip0 + 4 * MIsz;
  f16* pt0 = ip1 + 4 * MIsz;
  f16* pt1 = pt0 + 4 * MIsz;
  float* prc = (float*)(pool + 4 * (4 * MIsz * 2));

  k_cost<<<dim3(4), dim3(256), 0, stream>>>(gate, cost);
  k_split2<<<dim3(1024), dim3(256), 0, stream>>>(mu_w, w0, w1, MIsz);
  k_split2<<<dim3(1024), dim3(256), 0, stream>>>(in_proto, ip0, ip1, MIsz);
  k_split2<<<dim3(1024), dim3(256), 0, stream>>>(pt_w, pt0, pt1, MIsz);
  k_prc<<<dim3(8, 8, 4), dim3(256), 0, stream>>>(ip0, ip1, pt0, pt1, prc);
  k_pln2<<<dim3(4096), dim3(256), 0, stream>>>(prc, proto_w, pln_g, pln_b, ps0, ps1);

  for (int b0 = 0; b0 < NBATCH; b0 += C) {
    k_ln2<<<dim3(C * Ss), dim3(256), 0, stream>>>(x, ln1_g, ln1_b, h0, h1, b0);
    k_fqkv<<<dim3(16, 8, 3 * C), dim3(256), 0, stream>>>(h0, h1, w0, w1, ps0, ps1,
                                                         mu_b, cost, qkvb, C);
    k_trans<<<dim3(32, 16, 2 * C), dim3(256), 0, stream>>>(qkvb, vT0, vT1, C);
    k_scores<<<dim3(16, 16, C), dim3(256), 0, stream>>>(qkvb, scores, C);
    k_softmax2<<<dim3(Ss, 1, C), dim3(256), 0, stream>>>(scores, a0, a1);
    k_pv<<<dim3(16, 8, C), dim3(256), 0, stream>>>(a0, a1, vT0, vT1, ao0, ao1);
    k_fout<<<dim3(16, 8, C), dim3(256), 0, stream>>>(ao0, ao1,
                                                     w0 + 3 * MIsz, w1 + 3 * MIsz,
                                                     ps0 + 3 * MIsz, ps1 + 3 * MIsz,
                                                     mu_b + 3 * Dd, cost + 3 * Dd, x, out, b0);
  }
}

// Round 14
// 789.575 us; speedup vs baseline: 2.1172x; 1.0358x over previous
//
#include <hip/hip_runtime.h>
#include <math.h>

// MoIE transformer block on MFMA via f16-split f32 emulation.
// R14: R13 + drop the second-order (h1*p1) product from the fused cores
//      (contributes ~1.5e-7 to mv — 5 orders below the prc-path error that
//      dominates absmax). Fused cores: 7 -> 6 MFMA products.
// B=4, S=2048, D=1024.
#define Dd 1024
#define Ss 2048
#define NBATCH 4
#define LDSP 4096   // f16 per plane: 128 rows x 32

static constexpr size_t SDsz = (size_t)Ss * Dd;   // 2M elems
static constexpr size_t MIsz = (size_t)Dd * Dd;   // 1M elems
static constexpr size_t SSsz = (size_t)Ss * Ss;   // 4M elems
static constexpr float LN_EPS_ = 1e-5f;
static constexpr float GATE_EPS_ = 1e-9f;
static constexpr float SCALE_ = 1.0f / 32.0f;     // 1/sqrt(1024), exact

typedef _Float16 f16;
typedef _Float16 f16x8 __attribute__((ext_vector_type(8)));
typedef _Float16 f16x4 __attribute__((ext_vector_type(4)));
typedef float f32x4 __attribute__((ext_vector_type(4)));

__device__ __forceinline__ float silu_f(float v) { return v / (1.0f + __expf(-v)); }

__device__ __forceinline__ void split2(float x, f16& a, f16& b) {
  a = (f16)x; b = (f16)(x - (float)a);
}

// swizzled chunk offset (f16 elems) for 16B chunk c of row r within a plane
__device__ __forceinline__ int swz(int r, int c) {
  return r * 32 + ((c ^ ((r >> 1) & 3)) << 3);
}

// ---------------- block reductions (256 threads = 4 waves) ----------------
__device__ __forceinline__ float2 block_sum2(float2 v) {
#pragma unroll
  for (int o = 32; o > 0; o >>= 1) { v.x += __shfl_down(v.x, o); v.y += __shfl_down(v.y, o); }
  __shared__ float2 sm2[4];
  if ((threadIdx.x & 63) == 0) sm2[threadIdx.x >> 6] = v;
  __syncthreads();
  float2 r; r.x = sm2[0].x + sm2[1].x + sm2[2].x + sm2[3].x;
  r.y = sm2[0].y + sm2[1].y + sm2[2].y + sm2[3].y;
  __syncthreads();
  return r;
}
__device__ __forceinline__ float block_sum1(float v) {
#pragma unroll
  for (int o = 32; o > 0; o >>= 1) v += __shfl_down(v, o);
  __shared__ float sm1[4];
  if ((threadIdx.x & 63) == 0) sm1[threadIdx.x >> 6] = v;
  __syncthreads();
  float r = sm1[0] + sm1[1] + sm1[2] + sm1[3];
  __syncthreads();
  return r;
}
__device__ __forceinline__ float block_max1(float v) {
#pragma unroll
  for (int o = 32; o > 0; o >>= 1) v = fmaxf(v, __shfl_down(v, o));
  __shared__ float smm[4];
  if ((threadIdx.x & 63) == 0) smm[threadIdx.x >> 6] = v;
  __syncthreads();
  float r = fmaxf(fmaxf(smm[0], smm[1]), fmaxf(smm[2], smm[3]));
  __syncthreads();
  return r;
}

// ---------------- multi-plane MFMA GEMM core (16x16x32, reg-staged) ----------------
// acc += sum_{i+j<=MAXSUM} A_i * B_j^T over K; tile 128x128, 4 waves each 64x64.
template<int PLANES, int MAXSUM>
__device__ __forceinline__ void mp_core(
    f16* __restrict__ smem,
    const f16* __restrict__ Ap0, const f16* __restrict__ Ap1,
    const f16* __restrict__ Bp0, const f16* __restrict__ Bp1,
    int lda, int ldb, int m0, int n0, int kt_end, f32x4 acc[4][4]) {
  const f16* Ap[2] = {Ap0, Ap1};
  const f16* Bp[2] = {Bp0, Bp1};
  const int tid = threadIdx.x;
  const int l = tid & 63;
  const int wv = tid >> 6;
  const int wr = (wv >> 1) * 64, wc = (wv & 1) * 64;
  const int fl = l & 15, fq = l >> 4;
  const int r0 = tid >> 2, cc = tid & 3, kc = cc * 8;

  f16x8 ra[PLANES][2], rb[PLANES][2];
#pragma unroll
  for (int p = 0; p < PLANES; ++p) {
    ra[p][0] = *(const f16x8*)(Ap[p] + (size_t)(m0 + r0) * lda + kc);
    ra[p][1] = *(const f16x8*)(Ap[p] + (size_t)(m0 + 64 + r0) * lda + kc);
    rb[p][0] = *(const f16x8*)(Bp[p] + (size_t)(n0 + r0) * ldb + kc);
    rb[p][1] = *(const f16x8*)(Bp[p] + (size_t)(n0 + 64 + r0) * ldb + kc);
  }
  for (int kt = 0; kt < kt_end; ++kt) {
    __syncthreads();
#pragma unroll
    for (int p = 0; p < PLANES; ++p) {
      *(f16x8*)(smem + p * LDSP + swz(r0, cc)) = ra[p][0];
      *(f16x8*)(smem + p * LDSP + swz(64 + r0, cc)) = ra[p][1];
      *(f16x8*)(smem + (PLANES + p) * LDSP + swz(r0, cc)) = rb[p][0];
      *(f16x8*)(smem + (PLANES + p) * LDSP + swz(64 + r0, cc)) = rb[p][1];
    }
    __syncthreads();
    if (kt + 1 < kt_end) {
      const int ko = (kt + 1) * 32 + kc;
#pragma unroll
      for (int p = 0; p < PLANES; ++p) {
        ra[p][0] = *(const f16x8*)(Ap[p] + (size_t)(m0 + r0) * lda + ko);
        ra[p][1] = *(const f16x8*)(Ap[p] + (size_t)(m0 + 64 + r0) * lda + ko);
        rb[p][0] = *(const f16x8*)(Bp[p] + (size_t)(n0 + r0) * ldb + ko);
        rb[p][1] = *(const f16x8*)(Bp[p] + (size_t)(n0 + 64 + r0) * ldb + ko);
      }
    }
    f16x8 af[PLANES][4];
#pragma unroll
    for (int p = 0; p < PLANES; ++p)
#pragma unroll
      for (int fr = 0; fr < 4; ++fr)
        af[p][fr] = *(const f16x8*)(smem + p * LDSP + swz(wr + fr * 16 + fl, fq));
#pragma unroll
    for (int fc = 0; fc < 4; ++fc) {
      f16x8 bf[PLANES];
#pragma unroll
      for (int p = 0; p < PLANES; ++p)
        bf[p] = *(const f16x8*)(smem + (PLANES + p) * LDSP + swz(wc + fc * 16 + fl, fq));
#pragma unroll
      for (int i = 0; i < PLANES; ++i)
#pragma unroll
        for (int j = 0; j < PLANES; ++j)
          if (i + j <= MAXSUM) {
#pragma unroll
            for (int fr = 0; fr < 4; ++fr)
              acc[fr][fc] = __builtin_amdgcn_mfma_f32_16x16x32_f16(af[i][fr], bf[j], acc[fr][fc], 0, 0, 0);
          }
    }
  }
}

// ---------------- fused dual-acc core (all-LDS, 6 planes, 6 products) ----------------
// LDS planes: A0,A1 (h lo/hi), W0,W1, P0,P1.
// acc1 += h@W^T   products (0,0),(0,1),(1,0)
// acc2 += h@P^T   products (0,0),(0,1),(1,0)          [(1,1) ~2^-22, dropped]
__device__ __forceinline__ void fused_core(
    f16* __restrict__ smem,
    const f16* __restrict__ A0p, const f16* __restrict__ A1p,
    const f16* __restrict__ W0p, const f16* __restrict__ W1p,
    const f16* __restrict__ P0p, const f16* __restrict__ P1p,
    int lda, int ldb, int m0, int n0, int kt_end,
    f32x4 acc1[4][4], f32x4 acc2[4][4]) {
  const f16* As[2] = {A0p, A1p};
  const f16* Bs[4] = {W0p, W1p, P0p, P1p};
  const int tid = threadIdx.x;
  const int l = tid & 63;
  const int wv = tid >> 6;
  const int wr = (wv >> 1) * 64, wc = (wv & 1) * 64;
  const int fl = l & 15, fq = l >> 4;
  const int r0 = tid >> 2, cc = tid & 3, kc = cc * 8;

  f16x8 ra[2][2], rb[4][2];
#pragma unroll
  for (int p = 0; p < 2; ++p) {
    ra[p][0] = *(const f16x8*)(As[p] + (size_t)(m0 + r0) * lda + kc);
    ra[p][1] = *(const f16x8*)(As[p] + (size_t)(m0 + 64 + r0) * lda + kc);
  }
#pragma unroll
  for (int p = 0; p < 4; ++p) {
    rb[p][0] = *(const f16x8*)(Bs[p] + (size_t)(n0 + r0) * ldb + kc);
    rb[p][1] = *(const f16x8*)(Bs[p] + (size_t)(n0 + 64 + r0) * ldb + kc);
  }
  for (int kt = 0; kt < kt_end; ++kt) {
    __syncthreads();
#pragma unroll
    for (int p = 0; p < 2; ++p) {
      *(f16x8*)(smem + p * LDSP + swz(r0, cc)) = ra[p][0];
      *(f16x8*)(smem + p * LDSP + swz(64 + r0, cc)) = ra[p][1];
    }
#pragma unroll
    for (int p = 0; p < 4; ++p) {
      *(f16x8*)(smem + (2 + p) * LDSP + swz(r0, cc)) = rb[p][0];
      *(f16x8*)(smem + (2 + p) * LDSP + swz(64 + r0, cc)) = rb[p][1];
    }
    __syncthreads();
    if (kt + 1 < kt_end) {
      const int ko = (kt + 1) * 32 + kc;
#pragma unroll
      for (int p = 0; p < 2; ++p) {
        ra[p][0] = *(const f16x8*)(As[p] + (size_t)(m0 + r0) * lda + ko);
        ra[p][1] = *(const f16x8*)(As[p] + (size_t)(m0 + 64 + r0) * lda + ko);
      }
#pragma unroll
      for (int p = 0; p < 4; ++p) {
        rb[p][0] = *(const f16x8*)(Bs[p] + (size_t)(n0 + r0) * ldb + ko);
        rb[p][1] = *(const f16x8*)(Bs[p] + (size_t)(n0 + 64 + r0) * ldb + ko);
      }
    }
    f16x8 af0[4], af1[4];
#pragma unroll
    for (int fr = 0; fr < 4; ++fr) {
      af0[fr] = *(const f16x8*)(smem + 0 * LDSP + swz(wr + fr * 16 + fl, fq));
      af1[fr] = *(const f16x8*)(smem + 1 * LDSP + swz(wr + fr * 16 + fl, fq));
    }
#pragma unroll
    for (int fc = 0; fc < 4; ++fc) {
      f16x8 bw0 = *(const f16x8*)(smem + 2 * LDSP + swz(wc + fc * 16 + fl, fq));
      f16x8 bw1 = *(const f16x8*)(smem + 3 * LDSP + swz(wc + fc * 16 + fl, fq));
      f16x8 bp0 = *(const f16x8*)(smem + 4 * LDSP + swz(wc + fc * 16 + fl, fq));
      f16x8 bp1 = *(const f16x8*)(smem + 5 * LDSP + swz(wc + fc * 16 + fl, fq));
#pragma unroll
      for (int fr = 0; fr < 4; ++fr) {
        acc1[fr][fc] = __builtin_amdgcn_mfma_f32_16x16x32_f16(af0[fr], bw0, acc1[fr][fc], 0, 0, 0);
        acc2[fr][fc] = __builtin_amdgcn_mfma_f32_16x16x32_f16(af0[fr], bp0, acc2[fr][fc], 0, 0, 0);
        acc1[fr][fc] = __builtin_amdgcn_mfma_f32_16x16x32_f16(af0[fr], bw1, acc1[fr][fc], 0, 0, 0);
        acc2[fr][fc] = __builtin_amdgcn_mfma_f32_16x16x32_f16(af0[fr], bp1, acc2[fr][fc], 0, 0, 0);
        acc1[fr][fc] = __builtin_amdgcn_mfma_f32_16x16x32_f16(af1[fr], bw0, acc1[fr][fc], 0, 0, 0);
        acc2[fr][fc] = __builtin_amdgcn_mfma_f32_16x16x32_f16(af1[fr], bp0, acc2[fr][fc], 0, 0, 0);
      }
    }
  }
}

// epilogue iterators
template<class F>
__device__ __forceinline__ void epilogue(const f32x4 acc[4][4], int m0, int n0, F&& f) {
  const int tid = threadIdx.x;
  const int l = tid & 63;
  const int wv = tid >> 6;
  const int wr = (wv >> 1) * 64, wc = (wv & 1) * 64;
  const int fl = l & 15, fq = l >> 4;
#pragma unroll
  for (int fr = 0; fr < 4; ++fr)
#pragma unroll
    for (int fc = 0; fc < 4; ++fc) {
      f32x4 av = acc[fr][fc];
#pragma unroll
      for (int r = 0; r < 4; ++r)
        f(m0 + wr + fr * 16 + fq * 4 + r, n0 + wc + fc * 16 + fl, av[r]);
    }
}
template<class F>
__device__ __forceinline__ void epilogue2(const f32x4 a1[4][4], const f32x4 a2[4][4], int m0, int n0, F&& f) {
  const int tid = threadIdx.x;
  const int l = tid & 63;
  const int wv = tid >> 6;
  const int wr = (wv >> 1) * 64, wc = (wv & 1) * 64;
  const int fl = l & 15, fq = l >> 4;
#pragma unroll
  for (int fr = 0; fr < 4; ++fr)
#pragma unroll
    for (int fc = 0; fc < 4; ++fc) {
      f32x4 v1 = a1[fr][fc], v2 = a2[fr][fc];
#pragma unroll
      for (int r = 0; r < 4; ++r)
        f(m0 + wr + fr * 16 + fq * 4 + r, n0 + wc + fc * 16 + fl, v1[r], v2[r]);
    }
}

// ---------------- GEMM wrapper kernels ----------------

// prc = in_proto @ pt_w^T per expert (f16x2, 4 products — LN-amplified path)
__global__ __launch_bounds__(256, 3) void k_prc(const f16* __restrict__ ip0, const f16* __restrict__ ip1,
                                                const f16* __restrict__ pt0, const f16* __restrict__ pt1,
                                                float* __restrict__ prc) {
  __shared__ f16 smem[4 * LDSP];
  const int n = blockIdx.z;
  const int m0 = blockIdx.x * 128, n0 = blockIdx.y * 128;
  const size_t o = (size_t)n * MIsz;
  f32x4 acc[4][4] = {};
  mp_core<2, 2>(smem, ip0 + o, ip1 + o, pt0 + o, pt1 + o, Dd, Dd, m0, n0, Dd / 32, acc);
  float* Cp = prc + o;
  epilogue(acc, m0, n0, [&](int row, int col, float aval) {
    Cp[(size_t)row * Dd + col] = aval;
  });
}

// fused comp+mv
__global__ __launch_bounds__(256, 2) void k_fqkv(const f16* __restrict__ h0, const f16* __restrict__ h1,
                                                 const f16* __restrict__ w0, const f16* __restrict__ w1,
                                                 const f16* __restrict__ s0, const f16* __restrict__ s1,
                                                 const float* __restrict__ mu_b, const float* __restrict__ cost,
                                                 f16* __restrict__ qkvb, int C) {
  __shared__ f16 smem[6 * LDSP];
  const int z = blockIdx.z, n = z / C, cb = z - n * C;
  const int m0 = blockIdx.x * 128, n0 = blockIdx.y * 128;
  const size_t ao = (size_t)cb * SDsz, bo = (size_t)n * MIsz;
  f32x4 acc1[4][4] = {}, acc2[4][4] = {};
  fused_core(smem, h0 + ao, h1 + ao, w0 + bo, w1 + bo, s0 + bo, s1 + bo,
             Dd, Dd, m0, n0, Dd / 32, acc1, acc2);
  const float* bp = mu_b + (size_t)n * Dd;
  const float* cp = cost + (size_t)n * Dd;
  f16* o0 = qkvb + ((size_t)(2 * n) * C + cb) * SDsz;
  f16* o1 = qkvb + ((size_t)(2 * n + 1) * C + cb) * SDsz;
  epilogue2(acc1, acc2, m0, n0, [&](int row, int col, float v1, float v2) {
    bool m = (v2 * SCALE_ - cp[col]) > 0.f;
    float comp = m ? silu_f(v1 + bp[col]) : 0.f;
    f16 lo, hi; split2(comp, lo, hi);
    size_t idx = (size_t)row * Dd + col;
    o0[idx] = lo; o1[idx] = hi;
  });
}

// scores = q @ k^T * scale, causal tile-skip (3 products)
__global__ __launch_bounds__(256, 3) void k_scores(const f16* __restrict__ qkvb, float* __restrict__ scores, int C) {
  const int m0 = blockIdx.x * 128, n0 = blockIdx.y * 128;
  if (n0 >= m0 + 128) return;
  __shared__ f16 smem[4 * LDSP];
  const int cb = blockIdx.z;
  const f16* q0 = qkvb + ((size_t)0 * C + cb) * SDsz;
  const f16* q1 = qkvb + ((size_t)1 * C + cb) * SDsz;
  const f16* kk0 = qkvb + ((size_t)2 * C + cb) * SDsz;
  const f16* kk1 = qkvb + ((size_t)3 * C + cb) * SDsz;
  f32x4 acc[4][4] = {};
  mp_core<2, 1>(smem, q0, q1, kk0, kk1, Dd, Dd, m0, n0, Dd / 32, acc);
  float* Cp = scores + (size_t)cb * SSsz;
  epilogue(acc, m0, n0, [&](int row, int col, float aval) {
    Cp[(size_t)row * Ss + col] = aval * SCALE_;
  });
}

// attn_out = attn @ v (via vT), causal k-bound; split2 planes (3 products)
__global__ __launch_bounds__(256, 3) void k_pv(const f16* __restrict__ a0, const f16* __restrict__ a1,
                                               const f16* __restrict__ vT0, const f16* __restrict__ vT1,
                                               f16* __restrict__ ao0, f16* __restrict__ ao1) {
  __shared__ f16 smem[4 * LDSP];
  const int cb = blockIdx.z;
  const int m0 = blockIdx.x * 128, n0 = blockIdx.y * 128;
  const f16* A0 = a0 + (size_t)cb * SSsz;
  const f16* A1 = a1 + (size_t)cb * SSsz;
  const f16* B0 = vT0 + (size_t)cb * SDsz;
  const f16* B1 = vT1 + (size_t)cb * SDsz;
  const int kt_end = (m0 + 128) / 32;
  f32x4 acc[4][4] = {};
  mp_core<2, 1>(smem, A0, A1, B0, B1, Ss, Ss, m0, n0, kt_end, acc);
  f16* p0 = ao0 + (size_t)cb * SDsz;
  f16* p1 = ao1 + (size_t)cb * SDsz;
  epilogue(acc, m0, n0, [&](int row, int col, float aval) {
    f16 x0, x1; split2(aval, x0, x1);
    size_t idx = (size_t)row * Dd + col;
    p0[idx] = x0; p1[idx] = x1;
  });
}

// fused co+mvo
__global__ __launch_bounds__(256, 2) void k_fout(const f16* __restrict__ ao0, const f16* __restrict__ ao1,
                                                 const f16* __restrict__ w30, const f16* __restrict__ w31,
                                                 const f16* __restrict__ s30, const f16* __restrict__ s31,
                                                 const float* __restrict__ b3, const float* __restrict__ cost3,
                                                 const float* __restrict__ x, float* __restrict__ out, int b0) {
  __shared__ f16 smem[6 * LDSP];
  const int cb = blockIdx.z;
  const int m0 = blockIdx.x * 128, n0 = blockIdx.y * 128;
  const size_t ao = (size_t)cb * SDsz;
  f32x4 acc1[4][4] = {}, acc2[4][4] = {};
  fused_core(smem, ao0 + ao, ao1 + ao, w30, w31, s30, s31,
             Dd, Dd, m0, n0, Dd / 32, acc1, acc2);
  const float* xp = x + (size_t)(b0 + cb) * SDsz;
  float* op = out + (size_t)(b0 + cb) * SDsz;
  epilogue2(acc1, acc2, m0, n0, [&](int row, int col, float v1, float v2) {
    size_t idx = (size_t)row * Dd + col;
    bool m = (v2 * SCALE_ - cost3[col]) > 0.f;
    op[idx] = xp[idx] + (m ? silu_f(v1 + b3[col]) : 0.f);
  });
}

// ---------------- elementwise / small kernels ----------------
__global__ __launch_bounds__(256) void k_cost(const float* __restrict__ gate, float* __restrict__ cost) {
  int n = blockIdx.x;
  const float* g = gate + (size_t)n * Dd;
  float m = 0.f;
  for (int i = threadIdx.x; i < Dd; i += 256) m = fmaxf(m, fabsf(g[i]));
  m = block_max1(m);
  float inv = 1.0f / (m + GATE_EPS_);
  for (int i = threadIdx.x; i < Dd; i += 256) cost[(size_t)n * Dd + i] = g[i] * inv;
}

// LN(x) -> f16x2 planes for the current C-group
__global__ __launch_bounds__(256) void k_ln2(const float* __restrict__ x, const float* __restrict__ g,
                                             const float* __restrict__ b, f16* __restrict__ h0,
                                             f16* __restrict__ h1, int b0) {
  size_t row = blockIdx.x;
  const float* xr = x + ((size_t)b0 * Ss + row) * Dd;
  float4 v = ((const float4*)xr)[threadIdx.x];
  float2 s = {v.x + v.y + v.z + v.w, v.x * v.x + v.y * v.y + v.z * v.z + v.w * v.w};
  s = block_sum2(s);
  float mean = s.x * (1.0f / Dd);
  float var = s.y * (1.0f / Dd) - mean * mean;
  float rs = rsqrtf(var + LN_EPS_);
  float4 gg = ((const float4*)g)[threadIdx.x];
  float4 bb = ((const float4*)b)[threadIdx.x];
  float o[4];
  o[0] = (v.x - mean) * rs * gg.x + bb.x;
  o[1] = (v.y - mean) * rs * gg.y + bb.y;
  o[2] = (v.z - mean) * rs * gg.z + bb.z;
  o[3] = (v.w - mean) * rs * gg.w + bb.w;
  f16x4 p0, p1;
#pragma unroll
  for (int j = 0; j < 4; ++j) { f16 a_, b_; split2(o[j], a_, b_); p0[j] = a_; p1[j] = b_; }
  ((f16x4*)(h0 + row * Dd))[threadIdx.x] = p0;
  ((f16x4*)(h1 + row * Dd))[threadIdx.x] = p1;
}

// ps = proto_w + LN(prc)*pln_g + pln_b -> f16x2 planes
__global__ __launch_bounds__(256) void k_pln2(const float* __restrict__ prc, const float* __restrict__ proto_w,
                                              const float* __restrict__ pg, const float* __restrict__ pb,
                                              f16* __restrict__ s0, f16* __restrict__ s1) {
  size_t row = blockIdx.x;            // 0..4095
  int n = (int)(row >> 10);
  float4 v = ((const float4*)(prc + row * Dd))[threadIdx.x];
  float2 s = {v.x + v.y + v.z + v.w, v.x * v.x + v.y * v.y + v.z * v.z + v.w * v.w};
  s = block_sum2(s);
  float mean = s.x * (1.0f / Dd);
  float var = s.y * (1.0f / Dd) - mean * mean;
  float rs = rsqrtf(var + LN_EPS_);
  float4 gg = ((const float4*)(pg + (size_t)n * Dd))[threadIdx.x];
  float4 bb = ((const float4*)(pb + (size_t)n * Dd))[threadIdx.x];
  float4 pw = ((const float4*)(proto_w + row * Dd))[threadIdx.x];
  float o[4];
  o[0] = (v.x - mean) * rs * gg.x + bb.x + pw.x;
  o[1] = (v.y - mean) * rs * gg.y + bb.y + pw.y;
  o[2] = (v.z - mean) * rs * gg.z + bb.z + pw.z;
  o[3] = (v.w - mean) * rs * gg.w + bb.w + pw.w;
  f16x4 p0, p1;
#pragma unroll
  for (int j = 0; j < 4; ++j) { f16 a_, b_; split2(o[j], a_, b_); p0[j] = a_; p1[j] = b_; }
  ((f16x4*)(s0 + row * Dd))[threadIdx.x] = p0;
  ((f16x4*)(s1 + row * Dd))[threadIdx.x] = p1;
}

// generic f32 -> f16x2 plane split, grid-strided over float4 chunks
__global__ __launch_bounds__(256) void k_split2(const float* __restrict__ in, f16* __restrict__ p0,
                                                f16* __restrict__ p1, size_t n4) {
  size_t stride = (size_t)gridDim.x * 256;
  for (size_t i = (size_t)blockIdx.x * 256 + threadIdx.x; i < n4; i += stride) {
    float4 v = ((const float4*)in)[i];
    f16x4 lo, hi;
    f16 a_, b_;
    split2(v.x, a_, b_); lo[0] = a_; hi[0] = b_;
    split2(v.y, a_, b_); lo[1] = a_; hi[1] = b_;
    split2(v.z, a_, b_); lo[2] = a_; hi[2] = b_;
    split2(v.w, a_, b_); lo[3] = a_; hi[3] = b_;
    ((f16x4*)p0)[i] = lo;
    ((f16x4*)p1)[i] = hi;
  }
}

// transpose v planes [S][D] -> vT [D][S]
__global__ __launch_bounds__(256) void k_trans(const f16* __restrict__ qkvb, f16* __restrict__ vT0,
                                               f16* __restrict__ vT1, int C) {
  __shared__ f16 t[64][72];
  const int z = blockIdx.z, pl = z & 1, cb = z >> 1;
  const f16* in = qkvb + ((size_t)(4 + pl) * C + cb) * SDsz;
  f16* out = (pl ? vT1 : vT0) + (size_t)cb * SDsz;
  const int s0 = blockIdx.x * 64, d0 = blockIdx.y * 64;
  const int tid = threadIdx.x;
#pragma unroll
  for (int it = 0; it < 2; ++it) {
    int c = tid + it * 256;
    int r = c >> 3, c8 = (c & 7) * 8;
    *(f16x8*)&t[r][c8] = *(const f16x8*)(in + (size_t)(s0 + r) * Dd + d0 + c8);
  }
  __syncthreads();
#pragma unroll
  for (int it = 0; it < 2; ++it) {
    int c = tid + it * 256;
    int r = c >> 3, c8 = (c & 7) * 8;
    f16x8 o;
#pragma unroll
    for (int j = 0; j < 8; ++j) o[j] = t[c8 + j][r];
    *(f16x8*)(out + (size_t)(d0 + r) * Ss + s0 + c8) = o;
  }
}

// row softmax (causal) -> attn f16x2 planes
__global__ __launch_bounds__(256) void k_softmax2(const float* __restrict__ scores, f16* __restrict__ a0,
                                                  f16* __restrict__ a1) {
  const int q = blockIdx.x, cb = blockIdx.z;
  const float* row = scores + (size_t)cb * SSsz + (size_t)q * Ss;
  float4 v0 = ((const float4*)row)[threadIdx.x];
  float4 v1 = ((const float4*)row)[threadIdx.x + 256];
  int b0i = threadIdx.x * 4, b1i = (threadIdx.x + 256) * 4;
  v0.x = (b0i + 0 <= q) ? v0.x : -INFINITY;
  v0.y = (b0i + 1 <= q) ? v0.y : -INFINITY;
  v0.z = (b0i + 2 <= q) ? v0.z : -INFINITY;
  v0.w = (b0i + 3 <= q) ? v0.w : -INFINITY;
  v1.x = (b1i + 0 <= q) ? v1.x : -INFINITY;
  v1.y = (b1i + 1 <= q) ? v1.y : -INFINITY;
  v1.z = (b1i + 2 <= q) ? v1.z : -INFINITY;
  v1.w = (b1i + 3 <= q) ? v1.w : -INFINITY;
  float mx = fmaxf(fmaxf(fmaxf(v0.x, v0.y), fmaxf(v0.z, v0.w)),
                   fmaxf(fmaxf(v1.x, v1.y), fmaxf(v1.z, v1.w)));
  mx = block_max1(mx);
  v0.x = (b0i + 0 <= q) ? __expf(v0.x - mx) : 0.f;
  v0.y = (b0i + 1 <= q) ? __expf(v0.y - mx) : 0.f;
  v0.z = (b0i + 2 <= q) ? __expf(v0.z - mx) : 0.f;
  v0.w = (b0i + 3 <= q) ? __expf(v0.w - mx) : 0.f;
  v1.x = (b1i + 0 <= q) ? __expf(v1.x - mx) : 0.f;
  v1.y = (b1i + 1 <= q) ? __expf(v1.y - mx) : 0.f;
  v1.z = (b1i + 2 <= q) ? __expf(v1.z - mx) : 0.f;
  v1.w = (b1i + 3 <= q) ? __expf(v1.w - mx) : 0.f;
  float s = v0.x + v0.y + v0.z + v0.w + v1.x + v1.y + v1.z + v1.w;
  s = block_sum1(s);
  float inv = 1.0f / s;
  float p0a[4] = {v0.x * inv, v0.y * inv, v0.z * inv, v0.w * inv};
  float p1a[4] = {v1.x * inv, v1.y * inv, v1.z * inv, v1.w * inv};
  f16* r0 = a0 + (size_t)cb * SSsz + (size_t)q * Ss;
  f16* r1 = a1 + (size_t)cb * SSsz + (size_t)q * Ss;
  f16x4 lo0, hi0, lo1, hi1;
#pragma unroll
  for (int j = 0; j < 4; ++j) {
    f16 a_, b_;
    split2(p0a[j], a_, b_); lo0[j] = a_; hi0[j] = b_;
    split2(p1a[j], a_, b_); lo1[j] = a_; hi1[j] = b_;
  }
  ((f16x4*)r0)[threadIdx.x] = lo0;
  ((f16x4*)r0)[threadIdx.x + 256] = lo1;
  ((f16x4*)r1)[threadIdx.x] = hi0;
  ((f16x4*)r1)[threadIdx.x + 256] = hi1;
}

// ---------------- launch ----------------
extern "C" void kernel_launch(void* const* d_in, const int* in_sizes, int n_in,
                              void* d_out, int out_size, void* d_ws, size_t ws_size,
                              hipStream_t stream) {
  const float* x        = (const float*)d_in[0];
  const float* ln1_g    = (const float*)d_in[1];
  const float* ln1_b    = (const float*)d_in[2];
  const float* mu_w     = (const float*)d_in[3];
  const float* mu_b     = (const float*)d_in[4];
  const float* proto_w  = (const float*)d_in[5];
  const float* gate     = (const float*)d_in[6];
  const float* pt_w     = (const float*)d_in[7];
  const float* pln_g    = (const float*)d_in[8];
  const float* pln_b    = (const float*)d_in[9];
  const float* in_proto = (const float*)d_in[10];
  float* out = (float*)d_out;

  uint8_t* base = (uint8_t*)d_ws;
  size_t off = 0;
  auto take = [&](size_t b) -> uint8_t* {
    uint8_t* p = base + off;
    off = (off + b + 255) & ~(size_t)255;
    return p;
  };
  const size_t SDb = SDsz * 2;  // bytes per f16 batch-plane (4MB)
  // persistent
  f16* w0  = (f16*)take(4 * MIsz * 2);
  f16* w1  = (f16*)take(4 * MIsz * 2);
  f16* ps0 = (f16*)take(4 * MIsz * 2);
  f16* ps1 = (f16*)take(4 * MIsz * 2);
  float* cost = (float*)take(4096 * 4);
  const size_t poolOff = off;

  auto need = [&](int c) -> size_t { return poolOff + (size_t)c * 14 * SDb + (1u << 20); };
  int C = (ws_size >= need(4)) ? 4 : (ws_size >= need(2)) ? 2 : 1;

  uint8_t* pool = base + poolOff;
  // pool phase layout
  f16* h0 = (f16*)pool;
  f16* h1 = h0 + (size_t)C * SDsz;
  uint8_t* Rc = pool + (size_t)2 * C * SDb;   // 6C*SDb region
  uint8_t* Rq = Rc + (size_t)6 * C * SDb;     // 6C*SDb region
  // Rc phase A: scores f32 (4C*SDb) + vT planes (2C*SDb)
  float* scores = (float*)Rc;
  f16* vT0 = (f16*)(Rc + (size_t)C * SSsz * 4);
  f16* vT1 = vT0 + (size_t)C * SDsz;
  // Rc phase B (over scores region): ao planes
  f16* ao0 = (f16*)Rc;
  f16* ao1 = ao0 + (size_t)C * SDsz;
  // Rq: qkv planes (q0,q1,k0,k1,v0,v1), later attn planes over q/k part
  f16* qkvb = (f16*)Rq;
  f16* a0 = (f16*)Rq;
  f16* a1 = a0 + (size_t)C * SSsz;
  // prologue overlay at pool start (consumed before main loop)
  f16* ip0 = (f16*)pool;
  f16* ip1 = ip0 + 4 * MIsz;
  f16* pt0 = ip1 + 4 * MIsz;
  f16* pt1 = pt0 + 4 * MIsz;
  float* prc = (float*)(pool + 4 * (4 * MIsz * 2));

  k_cost<<<dim3(4), dim3(256), 0, stream>>>(gate, cost);
  k_split2<<<dim3(1024), dim3(256), 0, stream>>>(mu_w, w0, w1, MIsz);
  k_split2<<<dim3(1024), dim3(256), 0, stream>>>(in_proto, ip0, ip1, MIsz);
  k_split2<<<dim3(1024), dim3(256), 0, stream>>>(pt_w, pt0, pt1, MIsz);
  k_prc<<<dim3(8, 8, 4), dim3(256), 0, stream>>>(ip0, ip1, pt0, pt1, prc);
  k_pln2<<<dim3(4096), dim3(256), 0, stream>>>(prc, proto_w, pln_g, pln_b, ps0, ps1);

  for (int b0 = 0; b0 < NBATCH; b0 += C) {
    k_ln2<<<dim3(C * Ss), dim3(256), 0, stream>>>(x, ln1_g, ln1_b, h0, h1, b0);
    k_fqkv<<<dim3(16, 8, 3 * C), dim3(256), 0, stream>>>(h0, h1, w0, w1, ps0, ps1,
                                                         mu_b, cost, qkvb, C);
    k_trans<<<dim3(32, 16, 2 * C), dim3(256), 0, stream>>>(qkvb, vT0, vT1, C);
    k_scores<<<dim3(16, 16, C), dim3(256), 0, stream>>>(qkvb, scores, C);
    k_softmax2<<<dim3(Ss, 1, C), dim3(256), 0, stream>>>(scores, a0, a1);
    k_pv<<<dim3(16, 8, C), dim3(256), 0, stream>>>(a0, a1, vT0, vT1, ao0, ao1);
    k_fout<<<dim3(16, 8, C), dim3(256), 0, stream>>>(ao0, ao1,
                                                     w0 + 3 * MIsz, w1 + 3 * MIsz,
                                                     ps0 + 3 * MIsz, ps1 + 3 * MIsz,
                                                     mu_b + 3 * Dd, cost + 3 * Dd, x, out, b0);
  }
}